// Round 2
// baseline (689.119 us; speedup 1.0000x reference)
//
#include <hip/hip_runtime.h>
#include <math.h>

#define Bq 8
#define Nn 1024
#define IND 64
#define HIDD 96

__device__ __forceinline__ float elu_f(float x){ return x > 0.f ? x : __expf(x) - 1.f; }
__device__ __forceinline__ float lrelu_f(float x){ return x > 0.f ? x : 0.2f * x; }

// ---------------- pre: LayerNorm + Linear(64->96) + ELU ----------------
__global__ __launch_bounds__(256) void pre_kernel(
    const float* __restrict__ x, const float* __restrict__ ln_g, const float* __restrict__ ln_b,
    const float* __restrict__ w, const float* __restrict__ bias, float* __restrict__ x0)
{
    __shared__ float xs[32][68];          // stride 68 -> bank r*4+k, conflict-free
    __shared__ float wl[IND * HIDD];      // 24 KB
    __shared__ float gl[IND], bl[IND];
    __shared__ float mu[32], rv[32];
    const int t = threadIdx.x;
    const int i0 = blockIdx.x * 32, b = blockIdx.y;

    { // load W: 6144 floats = 1536 float4
        const float4* w4 = (const float4*)w;
        float4* wl4 = (float4*)wl;
        #pragma unroll
        for (int m = 0; m < 6; m++) wl4[t + 256 * m] = w4[t + 256 * m];
    }
    if (t < IND) { gl[t] = ln_g[t]; bl[t] = ln_b[t]; }
    { // load x tile: 32 rows x 64
        const float4* xg = (const float4*)(x + ((size_t)b * Nn + i0) * IND);
        #pragma unroll
        for (int m = 0; m < 2; m++) {
            int idx = t + 256 * m;                 // float4 index, 16 per row
            int r = idx >> 4, c4 = idx & 15;
            float4 v = xg[idx];
            xs[r][c4 * 4 + 0] = v.x; xs[r][c4 * 4 + 1] = v.y;
            xs[r][c4 * 4 + 2] = v.z; xs[r][c4 * 4 + 3] = v.w;
        }
    }
    __syncthreads();
    const int r = t >> 3, cg = t & 7;
    { // LN stats: 8 threads per row
        float s = 0.f, s2 = 0.f;
        #pragma unroll
        for (int k = 0; k < 8; k++) { float v = xs[r][cg * 8 + k]; s += v; s2 += v * v; }
        #pragma unroll
        for (int m = 1; m < 8; m <<= 1) { s += __shfl_xor(s, m); s2 += __shfl_xor(s2, m); }
        if (cg == 0) {
            float mean = s * (1.f / IND);
            mu[r] = mean;
            rv[r] = rsqrtf(s2 * (1.f / IND) - mean * mean + 1e-5f);
        }
    }
    __syncthreads();
    float acc[12];
    #pragma unroll
    for (int c = 0; c < 12; c++) acc[c] = 0.f;
    const float mur = mu[r], rvr = rv[r];
    for (int k = 0; k < IND; k++) {
        float xn = (xs[r][k] - mur) * rvr * gl[k] + bl[k];
        const float4* wrow = (const float4*)(&wl[k * HIDD + cg * 12]);
        #pragma unroll
        for (int q = 0; q < 3; q++) {
            float4 wv = wrow[q];
            acc[q * 4 + 0] += xn * wv.x; acc[q * 4 + 1] += xn * wv.y;
            acc[q * 4 + 2] += xn * wv.z; acc[q * 4 + 3] += xn * wv.w;
        }
    }
    #pragma unroll
    for (int c = 0; c < 12; c++) acc[c] = elu_f(acc[c] + bias[cg * 12 + c]);
    float4* o4 = (float4*)(x0 + ((size_t)b * Nn + i0 + r) * HIDD + cg * 12);
    o4[0] = make_float4(acc[0], acc[1], acc[2], acc[3]);
    o4[1] = make_float4(acc[4], acc[5], acc[6], acc[7]);
    o4[2] = make_float4(acc[8], acc[9], acc[10], acc[11]);
}

// ---------------- h = x_eff @ W ; e_src/e_dst per head ----------------
// mode 0: x_eff = xa
// mode 1: x_eff = (1-wt)*xa + wt*xb,   wt = gates[b*2+0]
// mode 2: x_eff = (1-wr)*xa + wr*xb,   wr = gates[b*2+1]
// mode 3: x_eff = xa + 0.5*(wt*xb + wr*xc)
template<int H>
__global__ __launch_bounds__(256) void h_kernel(
    const float* __restrict__ xa, const float* __restrict__ xb, const float* __restrict__ xc,
    const float* __restrict__ gates, int mode,
    const float* __restrict__ W, const float* __restrict__ a_s, const float* __restrict__ a_d,
    float* __restrict__ h_out, float* __restrict__ e_src, float* __restrict__ e_dst)
{
    __shared__ float xs[32][100];         // stride 100 -> conflict-free broadcast reads
    __shared__ float wl[HIDD * HIDD];     // 36 KB
    __shared__ float asl[HIDD], adl[HIDD];
    __shared__ float esl[32][H], edl[32][H];
    const int t = threadIdx.x;
    const int i0 = blockIdx.x * 32, b = blockIdx.y;

    { // load W: 9216 floats = 2304 float4
        const float4* w4 = (const float4*)W;
        float4* wl4 = (float4*)wl;
        #pragma unroll
        for (int m = 0; m < 9; m++) wl4[t + 256 * m] = w4[t + 256 * m];
    }
    if (t < HIDD) { asl[t] = a_s[t]; adl[t] = a_d[t]; }
    if (t < 32 * H) { ((float*)esl)[t] = 0.f; ((float*)edl)[t] = 0.f; }
    { // load x tile (mode-fused)
        float wt = 0.f, wr = 0.f;
        if (mode == 1) wt = gates[b * 2 + 0];
        else if (mode == 2) wt = gates[b * 2 + 1];
        else if (mode == 3) { wt = gates[b * 2 + 0]; wr = gates[b * 2 + 1]; }
        #pragma unroll
        for (int m = 0; m < 12; m++) {
            int idx = t + 256 * m;
            int r = idx / HIDD, k = idx % HIDD;
            size_t g = ((size_t)b * Nn + i0 + r) * HIDD + k;
            float v;
            if (mode == 0)       v = xa[g];
            else if (mode == 3)  v = xa[g] + 0.5f * (wt * xb[g] + wr * xc[g]);
            else                 v = (1.f - wt) * xa[g] + wt * xb[g];
            xs[r][k] = v;
        }
    }
    __syncthreads();
    const int r = t >> 3, cg = t & 7;
    float acc[12];
    #pragma unroll
    for (int c = 0; c < 12; c++) acc[c] = 0.f;
    for (int k = 0; k < HIDD; k++) {
        float xv = xs[r][k];
        const float4* wrow = (const float4*)(&wl[k * HIDD + cg * 12]);
        #pragma unroll
        for (int q = 0; q < 3; q++) {
            float4 wv = wrow[q];
            acc[q * 4 + 0] += xv * wv.x; acc[q * 4 + 1] += xv * wv.y;
            acc[q * 4 + 2] += xv * wv.z; acc[q * 4 + 3] += xv * wv.w;
        }
    }
    { // write h
        float4* o4 = (float4*)(h_out + ((size_t)b * Nn + i0 + r) * HIDD + cg * 12);
        o4[0] = make_float4(acc[0], acc[1], acc[2], acc[3]);
        o4[1] = make_float4(acc[4], acc[5], acc[6], acc[7]);
        o4[2] = make_float4(acc[8], acc[9], acc[10], acc[11]);
    }
    { // e partials -> LDS atomics
        float ps[H], pd[H];
        #pragma unroll
        for (int hh = 0; hh < H; hh++) { ps[hh] = 0.f; pd[hh] = 0.f; }
        #pragma unroll
        for (int c = 0; c < 12; c++) {
            int col = cg * 12 + c;
            int hh = (H == 3) ? (col >> 5) : 0;
            ps[hh] += acc[c] * asl[col];
            pd[hh] += acc[c] * adl[col];
        }
        #pragma unroll
        for (int hh = 0; hh < H; hh++) {
            if (H == 1 || ps[hh] != 0.f || pd[hh] != 0.f) {
                atomicAdd(&esl[r][hh], ps[hh]);
                atomicAdd(&edl[r][hh], pd[hh]);
            }
        }
    }
    __syncthreads();
    if (t < 32 * H) {
        int rr = t / H, hh = t % H;
        e_src[((size_t)b * H + hh) * Nn + i0 + rr] = esl[rr][hh];
        e_dst[((size_t)b * H + hh) * Nn + i0 + rr] = edl[rr][hh];
    }
}

// ---------------- per-row softmax stats: m_i, Z_i ----------------
__global__ __launch_bounds__(64) void stats_kernel(
    const int* __restrict__ adj, const float* __restrict__ e_src, const float* __restrict__ e_dst,
    int H, float* __restrict__ mbuf, float* __restrict__ zbuf)
{
    const int i = blockIdx.x, h = blockIdx.y, b = blockIdx.z;
    const int lane = threadIdx.x;
    const float es = e_src[((size_t)b * H + h) * Nn + i];
    const float* ed = e_dst + ((size_t)b * H + h) * Nn;
    const int* arow = adj + (size_t)i * Nn;
    float vals[16];
    float mx = -INFINITY;
    #pragma unroll
    for (int k = 0; k < 16; k++) {
        int j = lane + 64 * k;
        float v = lrelu_f(es + ed[j]);
        vals[k] = (arow[j] > 0) ? v : -INFINITY;
        mx = fmaxf(mx, vals[k]);
    }
    #pragma unroll
    for (int m = 1; m < 64; m <<= 1) mx = fmaxf(mx, __shfl_xor(mx, m));
    float s = 0.f;
    #pragma unroll
    for (int k = 0; k < 16; k++) s += __expf(vals[k] - mx);
    #pragma unroll
    for (int m = 1; m < 64; m <<= 1) s += __shfl_xor(s, m);
    if (lane == 0) {
        size_t o = ((size_t)b * H + h) * Nn + i;
        mbuf[o] = mx; zbuf[o] = s;
    }
}

// ---------------- weighted sum: out = ELU( (P @ h) / Z ) ----------------
template<int H>
__global__ __launch_bounds__(256) void ws_kernel(
    const int* __restrict__ adj, const float* __restrict__ h_g,
    const float* __restrict__ e_src, const float* __restrict__ e_dst,
    const float* __restrict__ mbuf, const float* __restrict__ zbuf,
    float* __restrict__ out)
{
    constexpr int DIM = HIDD / H;   // 96 or 32
    constexpr int CPT = DIM / 8;    // 12 or 4
    constexpr int D4 = DIM / 4;
    __shared__ float hl[128 * DIM];
    __shared__ float pl[32 * 132];  // stride 132 -> bank r*4+jj, conflict-free
    __shared__ float esr[32], mr[32], zr[32];
    const int t = threadIdx.x;
    const int i0 = blockIdx.x * 32, hh = blockIdx.y, b = blockIdx.z;
    if (t < 32) {
        size_t o = ((size_t)b * H + hh) * Nn + i0 + t;
        esr[t] = e_src[o]; mr[t] = mbuf[o]; zr[t] = zbuf[o];
    }
    const int r = t >> 3, cg = t & 7;
    const int pj = t & 127, prb = t >> 7;
    float acc[CPT];
    #pragma unroll
    for (int c = 0; c < CPT; c++) acc[c] = 0.f;
    __syncthreads();
    for (int jt = 0; jt < 8; jt++) {
        const int j0 = jt * 128;
        { // stage h tile: 128 x DIM
            const float4* hg4 = (const float4*)h_g;
            float4* hl4 = (float4*)hl;
            #pragma unroll
            for (int m = 0; m < DIM / 8; m++) {
                int idx = t + 256 * m;
                int row = idx / D4, c4 = idx % D4;
                hl4[idx] = hg4[((size_t)b * Nn + j0 + row) * (HIDD / 4) + hh * (DIM / 4) + c4];
            }
        }
        { // compute P tile: fixed col pj, 16 rows per thread
            float edj = e_dst[((size_t)b * H + hh) * Nn + j0 + pj];
            #pragma unroll
            for (int k = 0; k < 16; k++) {
                int pr = prb + 2 * k;
                int a = adj[(size_t)(i0 + pr) * Nn + j0 + pj];
                float v = (a > 0) ? __expf(lrelu_f(esr[pr] + edj) - mr[pr]) : 0.f;
                pl[pr * 132 + pj] = v;
            }
        }
        __syncthreads();
        const float4* hrow4 = (const float4*)hl;
        #pragma unroll 2
        for (int jj = 0; jj < 128; jj++) {
            float pv = pl[r * 132 + jj];
            #pragma unroll
            for (int q = 0; q < CPT / 4; q++) {
                float4 hv = hrow4[jj * D4 + cg * (CPT / 4) + q];
                acc[q * 4 + 0] += pv * hv.x; acc[q * 4 + 1] += pv * hv.y;
                acc[q * 4 + 2] += pv * hv.z; acc[q * 4 + 3] += pv * hv.w;
            }
        }
        __syncthreads();
    }
    const float invz = 1.f / zr[r];
    float4* o4 = (float4*)(out + ((size_t)b * Nn + i0 + r) * HIDD + hh * DIM + cg * CPT);
    #pragma unroll
    for (int q = 0; q < CPT / 4; q++) {
        float4 v;
        v.x = elu_f(acc[q * 4 + 0] * invz); v.y = elu_f(acc[q * 4 + 1] * invz);
        v.z = elu_f(acc[q * 4 + 2] * invz); v.w = elu_f(acc[q * 4 + 3] * invz);
        o4[q] = v;
    }
}

// ---------------- column means over N ----------------
__global__ __launch_bounds__(128) void mean_kernel(const float* __restrict__ in, float* __restrict__ out)
{
    const int b = blockIdx.x, c = threadIdx.x;
    if (c >= HIDD) return;
    float s0 = 0.f, s1 = 0.f, s2 = 0.f, s3 = 0.f;
    const float* p = in + (size_t)b * Nn * HIDD + c;
    for (int n = 0; n < Nn; n += 4) {
        s0 += p[(size_t)(n + 0) * HIDD];
        s1 += p[(size_t)(n + 1) * HIDD];
        s2 += p[(size_t)(n + 2) * HIDD];
        s3 += p[(size_t)(n + 3) * HIDD];
    }
    out[b * HIDD + c] = (s0 + s1 + s2 + s3) * (1.f / Nn);
}

// ---------------- gate MLP: sigmoid(ELU(pooled@w1+b1)@w2+b2) ----------------
__global__ __launch_bounds__(64) void gates_kernel(
    const float* __restrict__ x1m, const float* __restrict__ x2m,
    const float* __restrict__ w1, const float* __restrict__ b1,
    const float* __restrict__ w2, const float* __restrict__ b2,
    float* __restrict__ gates, float* __restrict__ d_out)
{
    __shared__ float pl[192], hid[48];
    const int b = blockIdx.x, t = threadIdx.x;
    for (int k = t; k < 192; k += 64)
        pl[k] = (k < HIDD) ? x1m[b * HIDD + k] : x2m[b * HIDD + k - HIDD];
    __syncthreads();
    if (t < 48) {
        float acc = b1[t];
        for (int k = 0; k < 192; k++) acc += pl[k] * w1[k * 48 + t];
        hid[t] = elu_f(acc);
    }
    __syncthreads();
    if (t < 2) {
        float acc = b2[t];
        for (int k = 0; k < 48; k++) acc += hid[k] * w2[k * 2 + t];
        float g = 1.f / (1.f + __expf(-acc));
        gates[b * 2 + t] = g;
        d_out[1024 + t * 8 + b] = g;     // outputs 1,2: gates[:,0], gates[:,1]
    }
}

// ---------------- final projection ----------------
__global__ __launch_bounds__(128) void proj_kernel(
    const float* __restrict__ x3m, const float* __restrict__ x4m, const float* __restrict__ x5m,
    const float* __restrict__ w, const float* __restrict__ bias, float* __restrict__ d_out)
{
    __shared__ float tok[288];
    const int b = blockIdx.x, t = threadIdx.x;
    if (t < HIDD) {
        tok[t] = x3m[b * HIDD + t];
        tok[HIDD + t] = x4m[b * HIDD + t];
        tok[2 * HIDD + t] = x5m[b * HIDD + t];
    }
    __syncthreads();
    float acc = bias[t];
    for (int k = 0; k < 288; k++) acc += tok[k] * w[k * 128 + t];
    d_out[b * 128 + t] = elu_f(acc);
}

extern "C" void kernel_launch(void* const* d_in, const int* in_sizes, int n_in,
                              void* d_out, int out_size, void* d_ws, size_t ws_size,
                              hipStream_t stream)
{
    const float* x     = (const float*)d_in[0];
    const int*   adj   = (const int*)d_in[1];
    const float* ln_g  = (const float*)d_in[2];
    const float* ln_b  = (const float*)d_in[3];
    const float* pre_w = (const float*)d_in[4];
    const float* pre_b = (const float*)d_in[5];
    const float* g_w[5]  = {(const float*)d_in[6],  (const float*)d_in[9],  (const float*)d_in[12],
                            (const float*)d_in[15], (const float*)d_in[18]};
    const float* g_as[5] = {(const float*)d_in[7],  (const float*)d_in[10], (const float*)d_in[13],
                            (const float*)d_in[16], (const float*)d_in[19]};
    const float* g_ad[5] = {(const float*)d_in[8],  (const float*)d_in[11], (const float*)d_in[14],
                            (const float*)d_in[17], (const float*)d_in[20]};
    const float* gw1 = (const float*)d_in[21];
    const float* gb1 = (const float*)d_in[22];
    const float* gw2 = (const float*)d_in[23];
    const float* gb2 = (const float*)d_in[24];
    const float* pw  = (const float*)d_in[25];
    const float* pb  = (const float*)d_in[26];
    float* out = (float*)d_out;

    float* ws = (float*)d_ws;
    const size_t SZ = (size_t)Bq * Nn * HIDD;   // 786432
    float* x0 = ws;
    float* x1 = ws + 1 * SZ;
    float* x2 = ws + 2 * SZ;
    float* x3 = ws + 3 * SZ;
    float* x4 = ws + 4 * SZ;
    float* x5 = ws + 5 * SZ;
    float* hb = ws + 6 * SZ;
    float* es = ws + 7 * SZ;
    float* ed = es + (size_t)Bq * 3 * Nn;
    float* mb = ed + (size_t)Bq * 3 * Nn;
    float* zb = mb + (size_t)Bq * 3 * Nn;
    float* x1m = zb + (size_t)Bq * 3 * Nn;
    float* x2m = x1m + Bq * HIDD;
    float* x3m = x2m + Bq * HIDD;
    float* x4m = x3m + Bq * HIDD;
    float* x5m = x4m + Bq * HIDD;
    float* gts = x5m + Bq * HIDD;

    const dim3 blk256(256), blk128(128), blk64(64);
    const dim3 grid_rows(Nn / 32, Bq);

    pre_kernel<<<grid_rows, blk256, 0, stream>>>(x, ln_g, ln_b, pre_w, pre_b, x0);

    // GAT1: 3 heads x 32, concat -> x1
    h_kernel<3><<<grid_rows, blk256, 0, stream>>>(x0, nullptr, nullptr, nullptr, 0,
                                                  g_w[0], g_as[0], g_ad[0], hb, es, ed);
    stats_kernel<<<dim3(Nn, 3, Bq), blk64, 0, stream>>>(adj, es, ed, 3, mb, zb);
    ws_kernel<3><<<dim3(Nn / 32, 3, Bq), blk256, 0, stream>>>(adj, hb, es, ed, mb, zb, x1);

    // GAT2: 1 head x 96 -> x2
    h_kernel<1><<<grid_rows, blk256, 0, stream>>>(x1, nullptr, nullptr, nullptr, 0,
                                                  g_w[1], g_as[1], g_ad[1], hb, es, ed);
    stats_kernel<<<dim3(Nn, 1, Bq), blk64, 0, stream>>>(adj, es, ed, 1, mb, zb);
    ws_kernel<1><<<dim3(Nn / 32, 1, Bq), blk256, 0, stream>>>(adj, hb, es, ed, mb, zb, x2);

    mean_kernel<<<dim3(Bq), blk128, 0, stream>>>(x1, x1m);
    mean_kernel<<<dim3(Bq), blk128, 0, stream>>>(x2, x2m);
    gates_kernel<<<dim3(Bq), blk64, 0, stream>>>(x1m, x2m, gw1, gb1, gw2, gb2, gts, out);

    // GAT4 on td_in = (1-wt)x1 + wt x2 -> x4
    h_kernel<1><<<grid_rows, blk256, 0, stream>>>(x1, x2, nullptr, gts, 1,
                                                  g_w[3], g_as[3], g_ad[3], hb, es, ed);
    stats_kernel<<<dim3(Nn, 1, Bq), blk64, 0, stream>>>(adj, es, ed, 1, mb, zb);
    ws_kernel<1><<<dim3(Nn / 32, 1, Bq), blk256, 0, stream>>>(adj, hb, es, ed, mb, zb, x4);

    // GAT5 on ra_in = (1-wr)x1 + wr x2 -> x5
    h_kernel<1><<<grid_rows, blk256, 0, stream>>>(x1, x2, nullptr, gts, 2,
                                                  g_w[4], g_as[4], g_ad[4], hb, es, ed);
    stats_kernel<<<dim3(Nn, 1, Bq), blk64, 0, stream>>>(adj, es, ed, 1, mb, zb);
    ws_kernel<1><<<dim3(Nn / 32, 1, Bq), blk256, 0, stream>>>(adj, hb, es, ed, mb, zb, x5);

    // GAT3 on stage_in = x2 + 0.5*(wt x4 + wr x5) -> x3
    h_kernel<1><<<grid_rows, blk256, 0, stream>>>(x2, x4, x5, gts, 3,
                                                  g_w[2], g_as[2], g_ad[2], hb, es, ed);
    stats_kernel<<<dim3(Nn, 1, Bq), blk64, 0, stream>>>(adj, es, ed, 1, mb, zb);
    ws_kernel<1><<<dim3(Nn / 32, 1, Bq), blk256, 0, stream>>>(adj, hb, es, ed, mb, zb, x3);

    mean_kernel<<<dim3(Bq), blk128, 0, stream>>>(x3, x3m);
    mean_kernel<<<dim3(Bq), blk128, 0, stream>>>(x4, x4m);
    mean_kernel<<<dim3(Bq), blk128, 0, stream>>>(x5, x5m);

    proj_kernel<<<dim3(Bq), blk128, 0, stream>>>(x3m, x4m, x5m, pw, pb, out);
}

// Round 3
// 372.182 us; speedup vs baseline: 1.8516x; 1.8516x over previous
//
#include <hip/hip_runtime.h>
#include <math.h>

#define Bq 8
#define Nn 1024
#define IND 64
#define HIDD 96

typedef __attribute__((ext_vector_type(8))) short bf16x8_t;  // 8 bf16 in 4 VGPRs
typedef __attribute__((ext_vector_type(4))) float f32x4_t;
typedef unsigned int u32;

__device__ __forceinline__ float elu_f(float x){ return x > 0.f ? x : __expf(x) - 1.f; }
__device__ __forceinline__ float lrelu_f(float x){ return x > 0.f ? x : 0.2f * x; }
__device__ __forceinline__ short f2bf(float f){            // RNE float->bf16
    union { float f; u32 u; } v; v.f = f;
    u32 r = (v.u + 0x7FFFu + ((v.u >> 16) & 1u)) >> 16;
    return (short)r;
}

// ---------------- adj bit-pack: adj[1024][1024] int -> adjp[1024][32] u32 ----------------
__global__ __launch_bounds__(256) void pack_adj(const int* __restrict__ adj, u32* __restrict__ adjp)
{
    int w = blockIdx.x * 256 + threadIdx.x;   // 32768 words
    int row = w >> 5, wc = w & 31;
    const int* p = adj + (size_t)row * Nn + wc * 32;
    u32 b = 0;
    #pragma unroll
    for (int e = 0; e < 32; e++) b |= (p[e] > 0 ? 1u : 0u) << e;
    adjp[w] = b;
}

// ---------------- pre: LayerNorm + Linear(64->96) + ELU ----------------
__global__ __launch_bounds__(256) void pre_kernel(
    const float* __restrict__ x, const float* __restrict__ ln_g, const float* __restrict__ ln_b,
    const float* __restrict__ w, const float* __restrict__ bias, float* __restrict__ x0)
{
    __shared__ float xs[32][68];
    __shared__ float wl[IND * HIDD];
    __shared__ float gl[IND], bl[IND];
    __shared__ float mu[32], rv[32];
    const int t = threadIdx.x;
    const int i0 = blockIdx.x * 32, b = blockIdx.y;

    {
        const float4* w4 = (const float4*)w;
        float4* wl4 = (float4*)wl;
        #pragma unroll
        for (int m = 0; m < 6; m++) wl4[t + 256 * m] = w4[t + 256 * m];
    }
    if (t < IND) { gl[t] = ln_g[t]; bl[t] = ln_b[t]; }
    {
        const float4* xg = (const float4*)(x + ((size_t)b * Nn + i0) * IND);
        #pragma unroll
        for (int m = 0; m < 2; m++) {
            int idx = t + 256 * m;
            int r = idx >> 4, c4 = idx & 15;
            float4 v = xg[idx];
            xs[r][c4 * 4 + 0] = v.x; xs[r][c4 * 4 + 1] = v.y;
            xs[r][c4 * 4 + 2] = v.z; xs[r][c4 * 4 + 3] = v.w;
        }
    }
    __syncthreads();
    const int r = t >> 3, cg = t & 7;
    {
        float s = 0.f, s2 = 0.f;
        #pragma unroll
        for (int k = 0; k < 8; k++) { float v = xs[r][cg * 8 + k]; s += v; s2 += v * v; }
        #pragma unroll
        for (int m = 1; m < 8; m <<= 1) { s += __shfl_xor(s, m); s2 += __shfl_xor(s2, m); }
        if (cg == 0) {
            float mean = s * (1.f / IND);
            mu[r] = mean;
            rv[r] = rsqrtf(s2 * (1.f / IND) - mean * mean + 1e-5f);
        }
    }
    __syncthreads();
    float acc[12];
    #pragma unroll
    for (int c = 0; c < 12; c++) acc[c] = 0.f;
    const float mur = mu[r], rvr = rv[r];
    for (int k = 0; k < IND; k++) {
        float xn = (xs[r][k] - mur) * rvr * gl[k] + bl[k];
        const float4* wrow = (const float4*)(&wl[k * HIDD + cg * 12]);
        #pragma unroll
        for (int q = 0; q < 3; q++) {
            float4 wv = wrow[q];
            acc[q * 4 + 0] += xn * wv.x; acc[q * 4 + 1] += xn * wv.y;
            acc[q * 4 + 2] += xn * wv.z; acc[q * 4 + 3] += xn * wv.w;
        }
    }
    #pragma unroll
    for (int c = 0; c < 12; c++) acc[c] = elu_f(acc[c] + bias[cg * 12 + c]);
    float4* o4 = (float4*)(x0 + ((size_t)b * Nn + i0 + r) * HIDD + cg * 12);
    o4[0] = make_float4(acc[0], acc[1], acc[2], acc[3]);
    o4[1] = make_float4(acc[4], acc[5], acc[6], acc[7]);
    o4[2] = make_float4(acc[8], acc[9], acc[10], acc[11]);
}

// ---------------- h = x_eff @ W ; writes h_t (bf16, transposed) + e_src/e_dst ----------------
struct HArgs {
    const float *xa, *xb, *xc;
    const float *W, *as_, *ad_;
    float *es, *ed;
    short *ht;           // bf16 [b][96][1024] transposed
    int mode;            // 0: xa; 1: (1-wt)xa+wt*xb; 2: (1-wr)xa+wr*xb; 3: xa+0.5(wt*xb+wr*xc)
};

template<int H>
__global__ __launch_bounds__(256) void h_kernel(HArgs a0, HArgs a1, const float* __restrict__ gates)
{
    __shared__ float xs[32][100];
    __shared__ float wl[HIDD * HIDD];     // 36 KB
    __shared__ float asl[HIDD], adl[HIDD];
    __shared__ float esl[32][H], edl_[32][H];
    __shared__ short htl[96][40];         // transpose staging (row stride 80B, 16B-aligned)
    const int t = threadIdx.x;
    const int i0 = blockIdx.x * 32, b = blockIdx.y;
    const HArgs A = (blockIdx.z == 0) ? a0 : a1;

    {
        const float4* w4 = (const float4*)A.W;
        float4* wl4 = (float4*)wl;
        #pragma unroll
        for (int m = 0; m < 9; m++) wl4[t + 256 * m] = w4[t + 256 * m];
    }
    if (t < HIDD) { asl[t] = A.as_[t]; adl[t] = A.ad_[t]; }
    if (t < 32 * H) { ((float*)esl)[t] = 0.f; ((float*)edl_)[t] = 0.f; }
    {
        float wt = 0.f, wr = 0.f;
        if (A.mode == 1) wt = gates[b * 2 + 0];
        else if (A.mode == 2) wt = gates[b * 2 + 1];
        else if (A.mode == 3) { wt = gates[b * 2 + 0]; wr = gates[b * 2 + 1]; }
        #pragma unroll
        for (int m = 0; m < 12; m++) {
            int idx = t + 256 * m;
            int r = idx / HIDD, k = idx % HIDD;
            size_t g = ((size_t)b * Nn + i0 + r) * HIDD + k;
            float v;
            if (A.mode == 0)       v = A.xa[g];
            else if (A.mode == 3)  v = A.xa[g] + 0.5f * (wt * A.xb[g] + wr * A.xc[g]);
            else                   v = (1.f - wt) * A.xa[g] + wt * A.xb[g];
            xs[r][k] = v;
        }
    }
    __syncthreads();
    const int r = t >> 3, cg = t & 7;
    float acc[12];
    #pragma unroll
    for (int c = 0; c < 12; c++) acc[c] = 0.f;
    for (int k = 0; k < HIDD; k++) {
        float xv = xs[r][k];
        const float4* wrow = (const float4*)(&wl[k * HIDD + cg * 12]);
        #pragma unroll
        for (int q = 0; q < 3; q++) {
            float4 wv = wrow[q];
            acc[q * 4 + 0] += xv * wv.x; acc[q * 4 + 1] += xv * wv.y;
            acc[q * 4 + 2] += xv * wv.z; acc[q * 4 + 3] += xv * wv.w;
        }
    }
    { // bf16 transpose into LDS
        #pragma unroll
        for (int c = 0; c < 12; c++) htl[cg * 12 + c][r] = f2bf(acc[c]);
    }
    { // e partials -> LDS atomics
        float ps[H], pd[H];
        #pragma unroll
        for (int hh = 0; hh < H; hh++) { ps[hh] = 0.f; pd[hh] = 0.f; }
        #pragma unroll
        for (int c = 0; c < 12; c++) {
            int col = cg * 12 + c;
            int hh = (H == 3) ? (col >> 5) : 0;
            ps[hh] += acc[c] * asl[col];
            pd[hh] += acc[c] * adl[col];
        }
        #pragma unroll
        for (int hh = 0; hh < H; hh++) {
            atomicAdd(&esl[r][hh], ps[hh]);
            atomicAdd(&edl_[r][hh], pd[hh]);
        }
    }
    __syncthreads();
    if (t < 32 * H) {
        int rr = t / H, hh = t % H;
        A.es[((size_t)b * H + hh) * Nn + i0 + rr] = esl[rr][hh];
        A.ed[((size_t)b * H + hh) * Nn + i0 + rr] = edl_[rr][hh];
    }
    if (t < 96) { // write transposed bf16 h_t rows
        uint4* dst = (uint4*)(A.ht + ((size_t)b * 96 + t) * Nn + i0);
        const uint4* src = (const uint4*)&htl[t][0];
        #pragma unroll
        for (int k = 0; k < 4; k++) dst[k] = src[k];
    }
}

// ---------------- ws: fused softmax-stats + MFMA P@h + ELU + column-mean accumulate ----------------
struct WArgs {
    const short* ht;     // bf16 [b][96][1024]
    const float* es;
    const float* ed;
    float* out;          // [b][1024][96]
    float* msum;         // [b][96] column-sum accumulator
};

template<int DIM, int NH, bool DUAL>
__global__ __launch_bounds__(256) void ws_kernel(const u32* __restrict__ adjp, WArgs a0, WArgs a1)
{
    constexpr int TPW = DIM / 32;              // 16x16 N-tiles per wave (3 for DIM=96, 1 for DIM=32)
    __shared__ float edl[1024];
    __shared__ u32 adjl[32][33];               // +1 pad: 16 rows same word-col -> distinct banks
    __shared__ float esl[32], ml[32], zl[32];
    __shared__ short htile[DIM][136];          // pad 136: 16-row b128 reads are 2-way (free)
    const int t = threadIdx.x;
    const int i0 = blockIdx.x * 32;
    const int hh = blockIdx.y;
    const int b  = blockIdx.z;
    const WArgs A = (DUAL && hh) ? a1 : a0;
    const int h_in = DUAL ? 0 : hh;
    const int colbase = h_in * DIM;

    ((float4*)edl)[t] = ((const float4*)(A.ed + ((size_t)b * NH + h_in) * Nn))[t];
    if (t < 32) esl[t] = A.es[((size_t)b * NH + h_in) * Nn + i0 + t];
    {
        int r = t >> 3, w4 = (t & 7) * 4;
        uint4 w = *((const uint4*)(adjp + (size_t)(i0 + r) * 32 + w4));
        adjl[r][w4] = w.x; adjl[r][w4 + 1] = w.y; adjl[r][w4 + 2] = w.z; adjl[r][w4 + 3] = w.w;
    }
    __syncthreads();

    { // pass 1: per-row max + Z (8 threads per row)
        int r = t >> 3, sub = t & 7;
        float es_r = esl[r];
        float mx = -1e30f;
        for (int w4 = 0; w4 < 4; w4++) {
            u32 word = adjl[r][sub * 4 + w4];
            #pragma unroll 8
            for (int e = 0; e < 32; e++) {
                if ((word >> e) & 1) {
                    float v = lrelu_f(es_r + edl[sub * 128 + w4 * 32 + e]);
                    mx = fmaxf(mx, v);
                }
            }
        }
        mx = fmaxf(mx, __shfl_xor(mx, 1));
        mx = fmaxf(mx, __shfl_xor(mx, 2));
        mx = fmaxf(mx, __shfl_xor(mx, 4));
        float sz = 0.f;
        for (int w4 = 0; w4 < 4; w4++) {
            u32 word = adjl[r][sub * 4 + w4];
            #pragma unroll 8
            for (int e = 0; e < 32; e++) {
                if ((word >> e) & 1) {
                    float v = lrelu_f(es_r + edl[sub * 128 + w4 * 32 + e]);
                    sz += __expf(v - mx);
                }
            }
        }
        sz += __shfl_xor(sz, 1);
        sz += __shfl_xor(sz, 2);
        sz += __shfl_xor(sz, 4);
        if (sub == 0) { ml[r] = mx; zl[r] = sz; }
    }
    __syncthreads();

    const int lane = t & 63, w = t >> 6;
    const int Mtile = w >> 1, Nbase = (w & 1) * TPW;
    const int rloc = Mtile * 16 + (lane & 15);   // A-frag row
    const int grp = lane >> 4;                   // k-group
    const float es_r = esl[rloc], m_r = ml[rloc];
    f32x4_t acc[TPW];
    #pragma unroll
    for (int n = 0; n < TPW; n++) acc[n] = (f32x4_t){0.f, 0.f, 0.f, 0.f};

    const uint4* src4 = (const uint4*)(A.ht + ((size_t)b * 96 + h_in * DIM) * Nn);
    for (int jt = 0; jt < 8; jt++) {
        __syncthreads();
        { // stage h_t tile [DIM][128] bf16
            #pragma unroll
            for (int m = 0; m < DIM / 16; m++) {
                int idx = t + 256 * m;
                int d = idx >> 4, c8 = idx & 15;
                *((uint4*)&htile[d][c8 * 8]) = src4[d * 128 + jt * 16 + c8];
            }
        }
        __syncthreads();
        #pragma unroll
        for (int ks = 0; ks < 4; ks++) {
            const int kbase = ks * 32 + 8 * grp;
            u32 bits = adjl[rloc][jt * 4 + ks] >> (8 * grp);
            const float* ep = &edl[jt * 128 + kbase];
            float4 e0 = *((const float4*)ep), e1 = *((const float4*)(ep + 4));
            float ev[8] = {e0.x, e0.y, e0.z, e0.w, e1.x, e1.y, e1.z, e1.w};
            bf16x8_t af;
            #pragma unroll
            for (int e = 0; e < 8; e++) {
                float v = lrelu_f(es_r + ev[e]);
                float p = __expf(v - m_r);
                af[e] = f2bf(((bits >> e) & 1) ? p : 0.f);
            }
            #pragma unroll
            for (int n = 0; n < TPW; n++) {
                int d = (Nbase + n) * 16 + (lane & 15);
                bf16x8_t bf = *((const bf16x8_t*)&htile[d][kbase]);
                acc[n] = __builtin_amdgcn_mfma_f32_16x16x32_bf16(af, bf, acc[n], 0, 0, 0);
            }
        }
    }

    // epilogue: divide by Z, ELU, store, accumulate column means
    #pragma unroll
    for (int n = 0; n < TPW; n++) {
        float csum = 0.f;
        const int cc = (Nbase + n) * 16 + (lane & 15);
        #pragma unroll
        for (int reg = 0; reg < 4; reg++) {
            int rr = Mtile * 16 + grp * 4 + reg;   // C/D: row=(lane>>4)*4+reg, col=lane&15
            float o = elu_f(acc[n][reg] / zl[rr]);
            A.out[((size_t)b * Nn + i0 + rr) * HIDD + colbase + cc] = o;
            csum += o;
        }
        csum += __shfl_xor(csum, 16);
        csum += __shfl_xor(csum, 32);
        if (lane < 16)
            atomicAdd(&A.msum[b * HIDD + colbase + (Nbase + n) * 16 + lane], csum);
    }
}

// ---------------- gate MLP: sigmoid(ELU(pooled@w1+b1)@w2+b2) ----------------
__global__ __launch_bounds__(64) void gates_kernel(
    const float* __restrict__ x1s, const float* __restrict__ x2s,
    const float* __restrict__ w1, const float* __restrict__ b1,
    const float* __restrict__ w2, const float* __restrict__ b2,
    float* __restrict__ gates, float* __restrict__ d_out)
{
    __shared__ float pl[192], hid[48];
    const int b = blockIdx.x, t = threadIdx.x;
    for (int k = t; k < 192; k += 64)
        pl[k] = ((k < HIDD) ? x1s[b * HIDD + k] : x2s[b * HIDD + k - HIDD]) * (1.f / Nn);
    __syncthreads();
    if (t < 48) {
        float acc = b1[t];
        for (int k = 0; k < 192; k++) acc += pl[k] * w1[k * 48 + t];
        hid[t] = elu_f(acc);
    }
    __syncthreads();
    if (t < 2) {
        float acc = b2[t];
        for (int k = 0; k < 48; k++) acc += hid[k] * w2[k * 2 + t];
        float g = 1.f / (1.f + __expf(-acc));
        gates[b * 2 + t] = g;
        d_out[1024 + t * 8 + b] = g;
    }
}

// ---------------- final projection ----------------
__global__ __launch_bounds__(128) void proj_kernel(
    const float* __restrict__ x3s, const float* __restrict__ x4s, const float* __restrict__ x5s,
    const float* __restrict__ w, const float* __restrict__ bias, float* __restrict__ d_out)
{
    __shared__ float tok[288];
    const int b = blockIdx.x, t = threadIdx.x;
    if (t < HIDD) {
        tok[t]            = x3s[b * HIDD + t] * (1.f / Nn);
        tok[HIDD + t]     = x4s[b * HIDD + t] * (1.f / Nn);
        tok[2 * HIDD + t] = x5s[b * HIDD + t] * (1.f / Nn);
    }
    __syncthreads();
    float acc = bias[t];
    for (int k = 0; k < 288; k++) acc += tok[k] * w[k * 128 + t];
    d_out[b * 128 + t] = elu_f(acc);
}

extern "C" void kernel_launch(void* const* d_in, const int* in_sizes, int n_in,
                              void* d_out, int out_size, void* d_ws, size_t ws_size,
                              hipStream_t stream)
{
    const float* x     = (const float*)d_in[0];
    const int*   adj   = (const int*)d_in[1];
    const float* ln_g  = (const float*)d_in[2];
    const float* ln_b  = (const float*)d_in[3];
    const float* pre_w = (const float*)d_in[4];
    const float* pre_b = (const float*)d_in[5];
    const float* g_w[5]  = {(const float*)d_in[6],  (const float*)d_in[9],  (const float*)d_in[12],
                            (const float*)d_in[15], (const float*)d_in[18]};
    const float* g_as[5] = {(const float*)d_in[7],  (const float*)d_in[10], (const float*)d_in[13],
                            (const float*)d_in[16], (const float*)d_in[19]};
    const float* g_ad[5] = {(const float*)d_in[8],  (const float*)d_in[11], (const float*)d_in[14],
                            (const float*)d_in[17], (const float*)d_in[20]};
    const float* gw1 = (const float*)d_in[21];
    const float* gb1 = (const float*)d_in[22];
    const float* gw2 = (const float*)d_in[23];
    const float* gb2 = (const float*)d_in[24];
    const float* pw  = (const float*)d_in[25];
    const float* pb  = (const float*)d_in[26];
    float* out = (float*)d_out;

    float* ws = (float*)d_ws;
    const size_t SZ = (size_t)Bq * Nn * HIDD;   // 786432
    float* x0 = ws;
    float* x1 = ws + 1 * SZ;
    float* x2 = ws + 2 * SZ;
    float* x3 = ws + 3 * SZ;
    float* x4 = ws + 4 * SZ;
    float* x5 = ws + 5 * SZ;
    float* esb = ws + 6 * SZ;            // up to 3*8*1024
    float* edb = esb + 24576;
    short* ht0 = (short*)(edb + 24576);  // bf16 [8][96][1024]
    short* ht1 = ht0 + (size_t)Bq * 96 * Nn;
    float* msb = (float*)(ht1 + (size_t)Bq * 96 * Nn);
    float* ms1 = msb, *ms2 = msb + 768, *ms3 = msb + 1536, *ms4 = msb + 2304, *ms5 = msb + 3072;
    float* gts = msb + 3840;
    u32*   adjp = (u32*)(gts + 16);

    const dim3 blk256(256);
    const dim3 grid_rows(Nn / 32, Bq);

    hipMemsetAsync(msb, 0, 3840 * sizeof(float), stream);
    pack_adj<<<dim3(128), blk256, 0, stream>>>(adj, adjp);
    pre_kernel<<<grid_rows, blk256, 0, stream>>>(x, ln_g, ln_b, pre_w, pre_b, x0);

    // GAT1: 3 heads x 32, concat -> x1
    {
        HArgs A; A.xa = x0; A.xb = nullptr; A.xc = nullptr;
        A.W = g_w[0]; A.as_ = g_as[0]; A.ad_ = g_ad[0];
        A.es = esb; A.ed = edb; A.ht = ht0; A.mode = 0;
        h_kernel<3><<<dim3(Nn / 32, Bq, 1), blk256, 0, stream>>>(A, A, gts);
        WArgs W0; W0.ht = ht0; W0.es = esb; W0.ed = edb; W0.out = x1; W0.msum = ms1;
        ws_kernel<32, 3, false><<<dim3(Nn / 32, 3, Bq), blk256, 0, stream>>>(adjp, W0, W0);
    }
    // GAT2 -> x2
    {
        HArgs A; A.xa = x1; A.xb = nullptr; A.xc = nullptr;
        A.W = g_w[1]; A.as_ = g_as[1]; A.ad_ = g_ad[1];
        A.es = esb; A.ed = edb; A.ht = ht0; A.mode = 0;
        h_kernel<1><<<dim3(Nn / 32, Bq, 1), blk256, 0, stream>>>(A, A, gts);
        WArgs W0; W0.ht = ht0; W0.es = esb; W0.ed = edb; W0.out = x2; W0.msum = ms2;
        ws_kernel<96, 1, false><<<dim3(Nn / 32, 1, Bq), blk256, 0, stream>>>(adjp, W0, W0);
    }
    gates_kernel<<<dim3(Bq), dim3(64), 0, stream>>>(ms1, ms2, gw1, gb1, gw2, gb2, gts, out);

    // GAT4 (td_in) + GAT5 (ra_in), batched dual -> x4, x5
    {
        HArgs A0; A0.xa = x1; A0.xb = x2; A0.xc = nullptr;
        A0.W = g_w[3]; A0.as_ = g_as[3]; A0.ad_ = g_ad[3];
        A0.es = esb; A0.ed = edb; A0.ht = ht0; A0.mode = 1;
        HArgs A1; A1.xa = x1; A1.xb = x2; A1.xc = nullptr;
        A1.W = g_w[4]; A1.as_ = g_as[4]; A1.ad_ = g_ad[4];
        A1.es = esb + 8192; A1.ed = edb + 8192; A1.ht = ht1; A1.mode = 2;
        h_kernel<1><<<dim3(Nn / 32, Bq, 2), blk256, 0, stream>>>(A0, A1, gts);
        WArgs W0; W0.ht = ht0; W0.es = esb; W0.ed = edb; W0.out = x4; W0.msum = ms4;
        WArgs W1; W1.ht = ht1; W1.es = esb + 8192; W1.ed = edb + 8192; W1.out = x5; W1.msum = ms5;
        ws_kernel<96, 1, true><<<dim3(Nn / 32, 2, Bq), blk256, 0, stream>>>(adjp, W0, W1);
    }
    // GAT3 on stage_in = x2 + 0.5*(wt x4 + wr x5) -> x3
    {
        HArgs A; A.xa = x2; A.xb = x4; A.xc = x5;
        A.W = g_w[2]; A.as_ = g_as[2]; A.ad_ = g_ad[2];
        A.es = esb; A.ed = edb; A.ht = ht0; A.mode = 3;
        h_kernel<1><<<dim3(Nn / 32, Bq, 1), blk256, 0, stream>>>(A, A, gts);
        WArgs W0; W0.ht = ht0; W0.es = esb; W0.ed = edb; W0.out = x3; W0.msum = ms3;
        ws_kernel<96, 1, false><<<dim3(Nn / 32, 1, Bq), blk256, 0, stream>>>(adjp, W0, W0);
    }

    proj_kernel<<<dim3(Bq), dim3(128), 0, stream>>>(ms3, ms4, ms5, pw, pb, out);
}

// Round 4
// 260.224 us; speedup vs baseline: 2.6482x; 1.4302x over previous
//
#include <hip/hip_runtime.h>
#include <math.h>

#define Bq 8
#define Nn 1024
#define IND 64
#define HIDD 96

typedef __attribute__((ext_vector_type(8))) short bf16x8_t;  // 8 bf16 in 4 VGPRs
typedef __attribute__((ext_vector_type(4))) float f32x4_t;
typedef unsigned int u32;

__device__ __forceinline__ float elu_f(float x){ return x > 0.f ? x : __expf(x) - 1.f; }
__device__ __forceinline__ float lrelu_f(float x){ return x > 0.f ? x : 0.2f * x; }
__device__ __forceinline__ short f2bf(float f){            // RNE float->bf16
    union { float f; u32 u; } v; v.f = f;
    u32 r = (v.u + 0x7FFFu + ((v.u >> 16) & 1u)) >> 16;
    return (short)r;
}

// ---------------- adj bit-pack: adj[1024][1024] int -> adjp[1024][32] u32 ----------------
__global__ __launch_bounds__(256) void pack_adj(const int* __restrict__ adj, u32* __restrict__ adjp)
{
    int w = blockIdx.x * 256 + threadIdx.x;   // 32768 words
    int row = w >> 5, wc = w & 31;
    const int* p = adj + (size_t)row * Nn + wc * 32;
    u32 b = 0;
    #pragma unroll
    for (int e = 0; e < 32; e++) b |= (p[e] > 0 ? 1u : 0u) << e;
    adjp[w] = b;
}

// ---------------- W prep: Wt[g][112][96] bf16, cols 96..96+2H-1 = a_src/a_dst ----------------
struct PrepArgs { const float *W, *as_, *ad_; int H; };
struct Prep5 { PrepArgs a[5]; };

__global__ __launch_bounds__(96) void prep_w(Prep5 p, short* __restrict__ Wt)
{
    const int c = blockIdx.x, g = blockIdx.y, k = threadIdx.x;  // c<112, k<96
    const PrepArgs A = p.a[g];
    float v = 0.f;
    if (c < 96) v = A.W[k * 96 + c];
    else {
        int q = c - 96, dim = 96 / A.H;
        if (q < A.H) { if (k >= q * dim && k < (q + 1) * dim) v = A.as_[k]; }
        else if (q < 2 * A.H) { int hh = q - A.H; if (k >= hh * dim && k < (hh + 1) * dim) v = A.ad_[k]; }
    }
    Wt[((size_t)g * 112 + c) * 96 + k] = f2bf(v);
}

// ---------------- pre: LayerNorm + Linear(64->96) + ELU (fp32) ----------------
__global__ __launch_bounds__(256) void pre_kernel(
    const float* __restrict__ x, const float* __restrict__ ln_g, const float* __restrict__ ln_b,
    const float* __restrict__ w, const float* __restrict__ bias, float* __restrict__ x0)
{
    __shared__ float xs[32][68];
    __shared__ float wl[IND * HIDD];
    __shared__ float gl[IND], bl[IND];
    __shared__ float mu[32], rv[32];
    const int t = threadIdx.x;
    const int i0 = blockIdx.x * 32, b = blockIdx.y;

    {
        const float4* w4 = (const float4*)w;
        float4* wl4 = (float4*)wl;
        #pragma unroll
        for (int m = 0; m < 6; m++) wl4[t + 256 * m] = w4[t + 256 * m];
    }
    if (t < IND) { gl[t] = ln_g[t]; bl[t] = ln_b[t]; }
    {
        const float4* xg = (const float4*)(x + ((size_t)b * Nn + i0) * IND);
        #pragma unroll
        for (int m = 0; m < 2; m++) {
            int idx = t + 256 * m;
            int r = idx >> 4, c4 = idx & 15;
            float4 v = xg[idx];
            xs[r][c4 * 4 + 0] = v.x; xs[r][c4 * 4 + 1] = v.y;
            xs[r][c4 * 4 + 2] = v.z; xs[r][c4 * 4 + 3] = v.w;
        }
    }
    __syncthreads();
    const int r = t >> 3, cg = t & 7;
    {
        float s = 0.f, s2 = 0.f;
        #pragma unroll
        for (int k = 0; k < 8; k++) { float v = xs[r][cg * 8 + k]; s += v; s2 += v * v; }
        #pragma unroll
        for (int m = 1; m < 8; m <<= 1) { s += __shfl_xor(s, m); s2 += __shfl_xor(s2, m); }
        if (cg == 0) {
            float mean = s * (1.f / IND);
            mu[r] = mean;
            rv[r] = rsqrtf(s2 * (1.f / IND) - mean * mean + 1e-5f);
        }
    }
    __syncthreads();
    float acc[12];
    #pragma unroll
    for (int c = 0; c < 12; c++) acc[c] = 0.f;
    const float mur = mu[r], rvr = rv[r];
    for (int k = 0; k < IND; k++) {
        float xn = (xs[r][k] - mur) * rvr * gl[k] + bl[k];
        const float4* wrow = (const float4*)(&wl[k * HIDD + cg * 12]);
        #pragma unroll
        for (int q = 0; q < 3; q++) {
            float4 wv = wrow[q];
            acc[q * 4 + 0] += xn * wv.x; acc[q * 4 + 1] += xn * wv.y;
            acc[q * 4 + 2] += xn * wv.z; acc[q * 4 + 3] += xn * wv.w;
        }
    }
    #pragma unroll
    for (int c = 0; c < 12; c++) acc[c] = elu_f(acc[c] + bias[cg * 12 + c]);
    float4* o4 = (float4*)(x0 + ((size_t)b * Nn + i0 + r) * HIDD + cg * 12);
    o4[0] = make_float4(acc[0], acc[1], acc[2], acc[3]);
    o4[1] = make_float4(acc[4], acc[5], acc[6], acc[7]);
    o4[2] = make_float4(acc[8], acc[9], acc[10], acc[11]);
}

// ---------------- h = x_eff @ W (MFMA); es/ed from extra W columns ----------------
struct HArgs {
    const float *xa, *xb, *xc;
    const short* Wt;      // [112][96] bf16 transposed-extended
    float *es, *ed;
    short *ht;            // bf16 [b][96][1024]
    int mode, H;          // mode 0:xa  1:(1-wt)xa+wt*xb  2:(1-wr)xa+wr*xb  3:xa+0.5(wt*xb+wr*xc)
};

__global__ __launch_bounds__(256) void h_mfma(HArgs a0, HArgs a1, const float* __restrict__ gates)
{
    const int t = threadIdx.x;
    const int lane = t & 63, w = t >> 6;
    const int node0 = blockIdx.x * 16;
    const int b = node0 >> 10, n0 = node0 & 1023;
    const HArgs A = blockIdx.y ? a1 : a0;
    const int row16 = lane & 15, grp = lane >> 4;

    float wt = 0.f, wr = 0.f;
    if (A.mode == 1) wt = gates[b * 2 + 0];
    else if (A.mode == 2) wt = gates[b * 2 + 1];
    else if (A.mode == 3) { wt = gates[b * 2 + 0]; wr = gates[b * 2 + 1]; }

    const size_t rowoff = (size_t)(node0 + row16) * HIDD;
    const int nt0 = (w < 3) ? 2 * w : 6;

    f32x4_t acc0 = {0.f,0.f,0.f,0.f}, acc1 = {0.f,0.f,0.f,0.f};
    #pragma unroll
    for (int ks = 0; ks < 3; ks++) {
        const int k0 = ks * 32 + grp * 8;
        float xv[8];
        {
            const float* pa = A.xa + rowoff + k0;
            float4 v0 = *(const float4*)pa, v1 = *(const float4*)(pa + 4);
            xv[0]=v0.x; xv[1]=v0.y; xv[2]=v0.z; xv[3]=v0.w;
            xv[4]=v1.x; xv[5]=v1.y; xv[6]=v1.z; xv[7]=v1.w;
        }
        if (A.mode == 1 || A.mode == 2) {
            const float* pb = A.xb + rowoff + k0;
            float4 u0 = *(const float4*)pb, u1 = *(const float4*)(pb + 4);
            float yv[8] = {u0.x,u0.y,u0.z,u0.w,u1.x,u1.y,u1.z,u1.w};
            #pragma unroll
            for (int e = 0; e < 8; e++) xv[e] = (1.f - wt) * xv[e] + wt * yv[e];
        } else if (A.mode == 3) {
            const float* pb = A.xb + rowoff + k0;
            const float* pc = A.xc + rowoff + k0;
            float4 u0 = *(const float4*)pb, u1 = *(const float4*)(pb + 4);
            float4 q0 = *(const float4*)pc, q1 = *(const float4*)(pc + 4);
            float yv[8] = {u0.x,u0.y,u0.z,u0.w,u1.x,u1.y,u1.z,u1.w};
            float zv[8] = {q0.x,q0.y,q0.z,q0.w,q1.x,q1.y,q1.z,q1.w};
            #pragma unroll
            for (int e = 0; e < 8; e++) xv[e] = xv[e] + 0.5f * (wt * yv[e] + wr * zv[e]);
        }
        bf16x8_t af;
        #pragma unroll
        for (int e = 0; e < 8; e++) af[e] = f2bf(xv[e]);

        {
            const short* wp0 = A.Wt + (size_t)(nt0 * 16 + row16) * 96 + k0;
            bf16x8_t bf0 = *(const bf16x8_t*)wp0;
            acc0 = __builtin_amdgcn_mfma_f32_16x16x32_bf16(af, bf0, acc0, 0, 0, 0);
        }
        if (w < 3) {
            const short* wp1 = A.Wt + (size_t)((nt0 + 1) * 16 + row16) * 96 + k0;
            bf16x8_t bf1 = *(const bf16x8_t*)wp1;
            acc1 = __builtin_amdgcn_mfma_f32_16x16x32_bf16(af, bf1, acc1, 0, 0, 0);
        }
    }
    if (w < 3) { // h columns -> ht bf16 transposed
        u32 lo0 = ((u32)(unsigned short)f2bf(acc0[0])) | (((u32)(unsigned short)f2bf(acc0[1])) << 16);
        u32 hi0 = ((u32)(unsigned short)f2bf(acc0[2])) | (((u32)(unsigned short)f2bf(acc0[3])) << 16);
        int c0 = nt0 * 16 + row16;
        *(uint2*)(A.ht + ((size_t)b * 96 + c0) * Nn + n0 + grp * 4) = make_uint2(lo0, hi0);
        u32 lo1 = ((u32)(unsigned short)f2bf(acc1[0])) | (((u32)(unsigned short)f2bf(acc1[1])) << 16);
        u32 hi1 = ((u32)(unsigned short)f2bf(acc1[2])) | (((u32)(unsigned short)f2bf(acc1[3])) << 16);
        int c1 = c0 + 16;
        *(uint2*)(A.ht + ((size_t)b * 96 + c1) * Nn + n0 + grp * 4) = make_uint2(lo1, hi1);
    } else { // es/ed columns
        int q = row16;
        if (q < 2 * A.H) {
            int head = (q < A.H) ? q : q - A.H;
            float* dst = ((q < A.H) ? A.es : A.ed) + ((size_t)b * A.H + head) * Nn + n0 + grp * 4;
            *(float4*)dst = make_float4(acc0[0], acc0[1], acc0[2], acc0[3]);
        }
    }
}

// ---------------- ws: P@h via MFMA, split-K over j across 4 waves, Z via ones-MFMA ----------------
struct WArgs {
    const short* ht;     // bf16 [b][96][1024]
    const float* es;
    const float* ed;
    float* out;          // fp32 [b][1024][96]
    float* msum;         // [b][96]
};

template<int DIM, int NH, bool DUAL>
__global__ __launch_bounds__(256) void ws_kernel(const u32* __restrict__ adjp, WArgs a0, WArgs a1)
{
    constexpr int NT = DIM / 16;           // 6 (DIM=96) or 2 (DIM=32)
    __shared__ u32 adjl[16][33];
    __shared__ float esl[16];
    __shared__ float red[4][16][DIM + 1];
    __shared__ float redz[4][16];
    __shared__ float colsum[DIM];
    const int t = threadIdx.x;
    const int i0 = blockIdx.x * 16;
    const int by = blockIdx.y, b = blockIdx.z;
    const WArgs A = (DUAL && by) ? a1 : a0;
    const int h_in = DUAL ? 0 : by;
    const int colbase = h_in * DIM;

    if (t < 128) {
        int r = t >> 3, w4 = (t & 7) * 4;
        uint4 wv = *(const uint4*)(adjp + (size_t)(i0 + r) * 32 + w4);
        adjl[r][w4] = wv.x; adjl[r][w4 + 1] = wv.y; adjl[r][w4 + 2] = wv.z; adjl[r][w4 + 3] = wv.w;
    }
    if (t < 16) esl[t] = A.es[((size_t)b * NH + h_in) * Nn + i0 + t];
    if (t < DIM) colsum[t] = 0.f;
    __syncthreads();

    const int lane = t & 63, w = t >> 6;
    const int row16 = lane & 15, grp = lane >> 4;
    const int jb = w * 256;
    const float es_r = esl[row16];
    const float* edp = A.ed + ((size_t)b * NH + h_in) * Nn + jb + grp * 8;
    const short* hrow = A.ht + ((size_t)b * 96 + colbase + row16) * Nn + jb + grp * 8;

    f32x4_t acc[NT];
    #pragma unroll
    for (int n = 0; n < NT; n++) acc[n] = (f32x4_t){0.f, 0.f, 0.f, 0.f};
    f32x4_t accz = {0.f, 0.f, 0.f, 0.f};
    bf16x8_t ones;
    #pragma unroll
    for (int e = 0; e < 8; e++) ones[e] = (short)0x3F80;

    #pragma unroll
    for (int ks = 0; ks < 8; ks++) {
        u32 bits = adjl[row16][w * 8 + ks] >> (grp * 8);
        float4 e0 = *(const float4*)(edp + ks * 32);
        float4 e1 = *(const float4*)(edp + ks * 32 + 4);
        float ev[8] = {e0.x, e0.y, e0.z, e0.w, e1.x, e1.y, e1.z, e1.w};
        bf16x8_t af;
        #pragma unroll
        for (int e = 0; e < 8; e++) {
            float p = __expf(lrelu_f(es_r + ev[e]));     // no max-shift: |e|<~6, fp32-safe
            af[e] = f2bf(((bits >> e) & 1) ? p : 0.f);
        }
        #pragma unroll
        for (int n = 0; n < NT; n++) {
            bf16x8_t bf = *(const bf16x8_t*)(hrow + n * 16 * Nn + ks * 32);
            acc[n] = __builtin_amdgcn_mfma_f32_16x16x32_bf16(af, bf, acc[n], 0, 0, 0);
        }
        accz = __builtin_amdgcn_mfma_f32_16x16x32_bf16(af, ones, accz, 0, 0, 0);
    }

    #pragma unroll
    for (int n = 0; n < NT; n++)
        #pragma unroll
        for (int reg = 0; reg < 4; reg++)
            red[w][grp * 4 + reg][n * 16 + row16] = acc[n][reg];
    if (row16 == 0) {
        #pragma unroll
        for (int reg = 0; reg < 4; reg++) redz[w][grp * 4 + reg] = accz[reg];
    }
    __syncthreads();

    #pragma unroll
    for (int q = 0; q < (16 * DIM) / 256; q++) {
        int idx = t + q * 256;
        int r = idx / DIM, c = idx % DIM;
        float s = red[0][r][c] + red[1][r][c] + red[2][r][c] + red[3][r][c];
        float z = redz[0][r] + redz[1][r] + redz[2][r] + redz[3][r];
        float o = elu_f(s / z);
        A.out[((size_t)b * Nn + i0 + r) * HIDD + colbase + c] = o;
        atomicAdd(&colsum[c], o);
    }
    __syncthreads();
    if (t < DIM) atomicAdd(&A.msum[b * HIDD + colbase + t], colsum[t]);
}

// ---------------- gate MLP ----------------
__global__ __launch_bounds__(64) void gates_kernel(
    const float* __restrict__ x1s, const float* __restrict__ x2s,
    const float* __restrict__ w1, const float* __restrict__ b1,
    const float* __restrict__ w2, const float* __restrict__ b2,
    float* __restrict__ gates, float* __restrict__ d_out)
{
    __shared__ float pl[192], hid[48];
    const int b = blockIdx.x, t = threadIdx.x;
    for (int k = t; k < 192; k += 64)
        pl[k] = ((k < HIDD) ? x1s[b * HIDD + k] : x2s[b * HIDD + k - HIDD]) * (1.f / Nn);
    __syncthreads();
    if (t < 48) {
        float acc = b1[t];
        for (int k = 0; k < 192; k++) acc += pl[k] * w1[k * 48 + t];
        hid[t] = elu_f(acc);
    }
    __syncthreads();
    if (t < 2) {
        float acc = b2[t];
        for (int k = 0; k < 48; k++) acc += hid[k] * w2[k * 2 + t];
        float g = 1.f / (1.f + __expf(-acc));
        gates[b * 2 + t] = g;
        d_out[1024 + t * 8 + b] = g;
    }
}

// ---------------- final projection ----------------
__global__ __launch_bounds__(128) void proj_kernel(
    const float* __restrict__ x3s, const float* __restrict__ x4s, const float* __restrict__ x5s,
    const float* __restrict__ w, const float* __restrict__ bias, float* __restrict__ d_out)
{
    __shared__ float tok[288];
    const int b = blockIdx.x, t = threadIdx.x;
    if (t < HIDD) {
        tok[t]            = x3s[b * HIDD + t] * (1.f / Nn);
        tok[HIDD + t]     = x4s[b * HIDD + t] * (1.f / Nn);
        tok[2 * HIDD + t] = x5s[b * HIDD + t] * (1.f / Nn);
    }
    __syncthreads();
    float acc = bias[t];
    for (int k = 0; k < 288; k++) acc += tok[k] * w[k * 128 + t];
    d_out[b * 128 + t] = elu_f(acc);
}

extern "C" void kernel_launch(void* const* d_in, const int* in_sizes, int n_in,
                              void* d_out, int out_size, void* d_ws, size_t ws_size,
                              hipStream_t stream)
{
    const float* x     = (const float*)d_in[0];
    const int*   adj   = (const int*)d_in[1];
    const float* ln_g  = (const float*)d_in[2];
    const float* ln_b  = (const float*)d_in[3];
    const float* pre_w = (const float*)d_in[4];
    const float* pre_b = (const float*)d_in[5];
    const float* g_w[5]  = {(const float*)d_in[6],  (const float*)d_in[9],  (const float*)d_in[12],
                            (const float*)d_in[15], (const float*)d_in[18]};
    const float* g_as[5] = {(const float*)d_in[7],  (const float*)d_in[10], (const float*)d_in[13],
                            (const float*)d_in[16], (const float*)d_in[19]};
    const float* g_ad[5] = {(const float*)d_in[8],  (const float*)d_in[11], (const float*)d_in[14],
                            (const float*)d_in[17], (const float*)d_in[20]};
    const float* gw1 = (const float*)d_in[21];
    const float* gb1 = (const float*)d_in[22];
    const float* gw2 = (const float*)d_in[23];
    const float* gb2 = (const float*)d_in[24];
    const float* pw  = (const float*)d_in[25];
    const float* pb  = (const float*)d_in[26];
    float* out = (float*)d_out;

    float* ws = (float*)d_ws;
    const size_t SZ = (size_t)Bq * Nn * HIDD;   // 786432
    float* x0 = ws;
    float* x1 = ws + 1 * SZ;
    float* x2 = ws + 2 * SZ;
    float* x3 = ws + 3 * SZ;
    float* x4 = ws + 4 * SZ;
    float* x5 = ws + 5 * SZ;
    float* esb = ws + 6 * SZ;            // 24576 (H up to 3)
    float* edb = esb + 24576;
    short* ht0 = (short*)(edb + 24576);  // bf16 [8][96][1024]
    short* ht1 = ht0 + (size_t)Bq * 96 * Nn;
    short* wtb = ht1 + (size_t)Bq * 96 * Nn;   // 5*112*96 bf16
    float* msb = (float*)(wtb + 5 * 112 * 96);
    float* ms1 = msb, *ms2 = msb + 768, *ms3 = msb + 1536, *ms4 = msb + 2304, *ms5 = msb + 3072;
    float* gts = msb + 3840;
    u32*   adjp = (u32*)(gts + 16);

    const dim3 blk256(256);

    hipMemsetAsync(msb, 0, 3840 * sizeof(float), stream);
    {
        Prep5 P;
        for (int g = 0; g < 5; g++) { P.a[g].W = g_w[g]; P.a[g].as_ = g_as[g]; P.a[g].ad_ = g_ad[g]; P.a[g].H = (g == 0) ? 3 : 1; }
        prep_w<<<dim3(112, 5), dim3(96), 0, stream>>>(P, wtb);
    }
    pack_adj<<<dim3(128), blk256, 0, stream>>>(adj, adjp);
    pre_kernel<<<dim3(Nn / 32, Bq), blk256, 0, stream>>>(x, ln_g, ln_b, pre_w, pre_b, x0);

    const dim3 hgrid1(Bq * Nn / 16, 1), hgrid2(Bq * Nn / 16, 2);

    // GAT1: 3 heads x 32 -> x1
    {
        HArgs A; A.xa = x0; A.xb = nullptr; A.xc = nullptr;
        A.Wt = wtb + 0 * 112 * 96; A.es = esb; A.ed = edb; A.ht = ht0; A.mode = 0; A.H = 3;
        h_mfma<<<hgrid1, blk256, 0, stream>>>(A, A, gts);
        WArgs W0; W0.ht = ht0; W0.es = esb; W0.ed = edb; W0.out = x1; W0.msum = ms1;
        ws_kernel<32, 3, false><<<dim3(Nn / 16, 3, Bq), blk256, 0, stream>>>(adjp, W0, W0);
    }
    // GAT2 -> x2
    {
        HArgs A; A.xa = x1; A.xb = nullptr; A.xc = nullptr;
        A.Wt = wtb + 1 * 112 * 96; A.es = esb; A.ed = edb; A.ht = ht0; A.mode = 0; A.H = 1;
        h_mfma<<<hgrid1, blk256, 0, stream>>>(A, A, gts);
        WArgs W0; W0.ht = ht0; W0.es = esb; W0.ed = edb; W0.out = x2; W0.msum = ms2;
        ws_kernel<96, 1, false><<<dim3(Nn / 16, 1, Bq), blk256, 0, stream>>>(adjp, W0, W0);
    }
    gates_kernel<<<dim3(Bq), dim3(64), 0, stream>>>(ms1, ms2, gw1, gb1, gw2, gb2, gts, out);

    // GAT4 (td_in) + GAT5 (ra_in) dual -> x4, x5
    {
        HArgs A0; A0.xa = x1; A0.xb = x2; A0.xc = nullptr;
        A0.Wt = wtb + 3 * 112 * 96; A0.es = esb; A0.ed = edb; A0.ht = ht0; A0.mode = 1; A0.H = 1;
        HArgs A1; A1.xa = x1; A1.xb = x2; A1.xc = nullptr;
        A1.Wt = wtb + 4 * 112 * 96; A1.es = esb + 8192; A1.ed = edb + 8192; A1.ht = ht1; A1.mode = 2; A1.H = 1;
        h_mfma<<<hgrid2, blk256, 0, stream>>>(A0, A1, gts);
        WArgs W0; W0.ht = ht0; W0.es = esb; W0.ed = edb; W0.out = x4; W0.msum = ms4;
        WArgs W1; W1.ht = ht1; W1.es = esb + 8192; W1.ed = edb + 8192; W1.out = x5; W1.msum = ms5;
        ws_kernel<96, 1, true><<<dim3(Nn / 16, 2, Bq), blk256, 0, stream>>>(adjp, W0, W1);
    }
    // GAT3 on stage_in = x2 + 0.5*(wt x4 + wr x5) -> x3
    {
        HArgs A; A.xa = x2; A.xb = x4; A.xc = x5;
        A.Wt = wtb + 2 * 112 * 96; A.es = esb; A.ed = edb; A.ht = ht0; A.mode = 3; A.H = 1;
        h_mfma<<<hgrid1, blk256, 0, stream>>>(A, A, gts);
        WArgs W0; W0.ht = ht0; W0.es = esb; W0.ed = edb; W0.out = x3; W0.msum = ms3;
        ws_kernel<96, 1, false><<<dim3(Nn / 16, 1, Bq), blk256, 0, stream>>>(adjp, W0, W0);
    }

    proj_kernel<<<dim3(Bq), dim3(128), 0, stream>>>(ms3, ms4, ms5, pw, pb, out);
}

// Round 5
// 242.581 us; speedup vs baseline: 2.8408x; 1.0727x over previous
//
#include <hip/hip_runtime.h>
#include <math.h>

#define Bq 8
#define Nn 1024

typedef __attribute__((ext_vector_type(8))) short bf16x8_t;
typedef __attribute__((ext_vector_type(4))) float f32x4_t;
typedef unsigned int u32;

__device__ __forceinline__ float elu_f(float x){ return x > 0.f ? x : __expf(x) - 1.f; }
__device__ __forceinline__ float lrelu_f(float x){ return x > 0.f ? x : 0.2f * x; }
__device__ __forceinline__ short f2bf(float f){            // RNE float->bf16
    union { float f; u32 u; } v; v.f = f;
    return (short)((v.u + 0x7FFFu + ((v.u >> 16) & 1u)) >> 16);
}
__device__ __forceinline__ u32 pk2(float a, float b){
    return (u32)(unsigned short)f2bf(a) | ((u32)(unsigned short)f2bf(b) << 16);
}
__device__ __forceinline__ bf16x8_t cvt8(const float* p){
    bf16x8_t r;
    #pragma unroll
    for (int e = 0; e < 8; e++) r[e] = f2bf(p[e]);
    return r;
}

// =========== setup: pack adj bits, build extended bf16 weights, zero accumulators ===========
// Wte[g][c][k]: c<96 -> W[k][c];  c=96+q (q<H) -> (W @ a_src_head_q)[k];  c=96+H+q -> (W @ a_dst_head_q)[k]
struct PrepP {
    const float *W0,*W1,*W2,*W3,*W4;
    const float *s0,*s1,*s2,*s3,*s4;
    const float *d0,*d1,*d2,*d3,*d4;
};

__global__ __launch_bounds__(256) void setup_kernel(
    PrepP P, const int* __restrict__ adj, const float* __restrict__ pre_w,
    u32* __restrict__ adjp, short* __restrict__ wtb, short* __restrict__ wpre,
    float* __restrict__ msz)
{
    const int bid = blockIdx.x, t = threadIdx.x;
    if (bid < 128) {                      // pack adj -> bitmask [1024][32]
        int w = bid * 256 + t;
        int row = w >> 5, wc = w & 31;
        const int* p = adj + (size_t)row * Nn + wc * 32;
        u32 bset = 0;
        #pragma unroll
        for (int e = 0; e < 32; e++) bset |= (p[e] > 0 ? 1u : 0u) << e;
        adjp[w] = bset;
    } else if (bid < 338) {               // extended W: 5 x 112 x 96
        int idx = (bid - 128) * 256 + t;
        int g = idx / 10752, rem = idx % 10752;
        int c = rem / 96, k = rem % 96;
        const float* W  = (g==0)?P.W0:(g==1)?P.W1:(g==2)?P.W2:(g==3)?P.W3:P.W4;
        const float* as = (g==0)?P.s0:(g==1)?P.s1:(g==2)?P.s2:(g==3)?P.s3:P.s4;
        const float* ad = (g==0)?P.d0:(g==1)?P.d1:(g==2)?P.d2:(g==3)?P.d3:P.d4;
        const int H = (g == 0) ? 3 : 1, dim = 96 / H;
        float v = 0.f;
        if (c < 96) v = W[k * 96 + c];
        else {
            int q = c - 96;
            if (q < H) {
                int base = q * dim; float s = 0.f;
                for (int d = 0; d < dim; d++) s += W[k * 96 + base + d] * as[base + d];
                v = s;
            } else if (q < 2 * H) {
                int base = (q - H) * dim; float s = 0.f;
                for (int d = 0; d < dim; d++) s += W[k * 96 + base + d] * ad[base + d];
                v = s;
            }
        }
        wtb[idx] = f2bf(v);
    } else if (bid < 362) {               // pre_w transposed [96][64] bf16
        int idx = (bid - 338) * 256 + t;
        int c = idx >> 6, k = idx & 63;
        wpre[idx] = f2bf(pre_w[k * 96 + c]);
    } else {                              // zero ms1..ms5 + gts
        int idx = (bid - 362) * 256 + t;
        if (idx < 3856) msz[idx] = 0.f;
    }
}

// =========== pre (LN + Linear 64->96 + ELU) fused with h1 GEMM + es1/ed1 ===========
__global__ __launch_bounds__(256) void pre_h1(
    const float* __restrict__ x, const float* __restrict__ ln_g, const float* __restrict__ ln_b,
    const short* __restrict__ wpre, const float* __restrict__ pre_b,
    const short* __restrict__ Wt1, short* __restrict__ ht1,
    float* __restrict__ es1, float* __restrict__ ed1)
{
    __shared__ short xsA[16][72];     // bf16 LN'd input rows
    __shared__ float xs0[16][100];    // fp32 x0 rows
    const int t = threadIdx.x;
    const int bid = blockIdx.x;
    const int b = bid >> 6, n0 = (bid & 63) * 16;
    {
        int r = t >> 4, c4 = t & 15;
        float4 v = *(const float4*)(x + ((size_t)b * Nn + n0 + r) * 64 + c4 * 4);
        float s = v.x + v.y + v.z + v.w;
        float s2 = v.x*v.x + v.y*v.y + v.z*v.z + v.w*v.w;
        #pragma unroll
        for (int m = 1; m < 16; m <<= 1) { s += __shfl_xor(s, m); s2 += __shfl_xor(s2, m); }
        float mu = s * (1.f / 64), rv = rsqrtf(s2 * (1.f / 64) - mu * mu + 1e-5f);
        float4 g = *(const float4*)(ln_g + c4 * 4);
        float4 bb = *(const float4*)(ln_b + c4 * 4);
        float xn0 = (v.x - mu) * rv * g.x + bb.x;
        float xn1 = (v.y - mu) * rv * g.y + bb.y;
        float xn2 = (v.z - mu) * rv * g.z + bb.z;
        float xn3 = (v.w - mu) * rv * g.w + bb.w;
        *(uint2*)&xsA[r][c4 * 4] = make_uint2(pk2(xn0, xn1), pk2(xn2, xn3));
    }
    __syncthreads();
    const int lane = t & 63, w = t >> 6;
    const int row16 = lane & 15, grp = lane >> 4;
    for (int tile = w; tile < 6; tile += 4) {    // pre GEMM (K=64)
        f32x4_t acc = {0.f,0.f,0.f,0.f};
        #pragma unroll
        for (int ks = 0; ks < 2; ks++) {
            int k0 = ks * 32 + grp * 8;
            bf16x8_t af = *(const bf16x8_t*)&xsA[row16][k0];
            bf16x8_t bf = *(const bf16x8_t*)(wpre + (size_t)(tile * 16 + row16) * 64 + k0);
            acc = __builtin_amdgcn_mfma_f32_16x16x32_bf16(af, bf, acc, 0, 0, 0);
        }
        int col = tile * 16 + row16;
        float pbv = pre_b[col];
        #pragma unroll
        for (int reg = 0; reg < 4; reg++)
            xs0[grp * 4 + reg][col] = elu_f(acc[reg] + pbv);
    }
    __syncthreads();
    for (int tile = w; tile < 7; tile += 4) {    // h1 GEMM (K=96) + es/ed tile
        f32x4_t acc = {0.f,0.f,0.f,0.f};
        #pragma unroll
        for (int ks = 0; ks < 3; ks++) {
            int k0 = ks * 32 + grp * 8;
            bf16x8_t af = cvt8(&xs0[row16][k0]);
            bf16x8_t bf = *(const bf16x8_t*)(Wt1 + (size_t)(tile * 16 + row16) * 96 + k0);
            acc = __builtin_amdgcn_mfma_f32_16x16x32_bf16(af, bf, acc, 0, 0, 0);
        }
        int col = tile * 16 + row16;
        if (tile < 6) {
            *(uint2*)(ht1 + ((size_t)b * 96 + col) * Nn + n0 + grp * 4) =
                make_uint2(pk2(acc[0], acc[1]), pk2(acc[2], acc[3]));
        } else {
            int q = row16;
            if (q < 3)
                *(float4*)(es1 + ((size_t)b * 3 + q) * Nn + n0 + grp * 4) =
                    make_float4(acc[0], acc[1], acc[2], acc[3]);
            else if (q < 6)
                *(float4*)(ed1 + ((size_t)b * 3 + (q - 3)) * Nn + n0 + grp * 4) =
                    make_float4(acc[0], acc[1], acc[2], acc[3]);
        }
    }
}

// =========== fused GAT step: attention (P@h via MFMA, split-K) + next-layer GEMMs ===========
struct WSArgs {
    const float *es, *ed;        // [b][NH][1024]
    const short *ht;             // [b][96][1024] bf16
    float *ms;                   // [b][96] column-sum accumulator
    int nmat, mode0;             // mode0: 1 = fp32 T-buf, 2 = final bf16 ht + es/ed
    const short *W0, *W1, *W2;   // extended weights [112][96]
    float *T0, *T1, *T2;         // fp32 T-bufs [b][112][1024]
    short *oHt; float *oEs, *oEd;
};

template<int NH>
__global__ __launch_bounds__(256) void ws_fused(const u32* __restrict__ adjp, WSArgs a0, WSArgs a1)
{
    constexpr int DIMH = 96 / NH, NT = DIMH / 16;
    __shared__ float xrows[16][100];
    __shared__ float red[4][16][97];
    __shared__ float redz[4][16];
    __shared__ u32 adjl[16][33];
    __shared__ float esl[NH * 16];
    const int t = threadIdx.x;
    const int i0 = blockIdx.x * 16, b = blockIdx.z;
    const WSArgs A = blockIdx.y ? a1 : a0;

    if (t < 128) {
        int r = t >> 3, w4 = (t & 7) * 4;
        uint4 wv = *(const uint4*)(adjp + (size_t)(i0 + r) * 32 + w4);
        adjl[r][w4] = wv.x; adjl[r][w4+1] = wv.y; adjl[r][w4+2] = wv.z; adjl[r][w4+3] = wv.w;
    }
    if (t < NH * 16)
        esl[t] = A.es[((size_t)b * NH + (t >> 4)) * Nn + i0 + (t & 15)];
    __syncthreads();

    const int lane = t & 63, w = t >> 6;
    const int row16 = lane & 15, grp = lane >> 4;
    const int jb = w * 256;
    bf16x8_t ones;
    #pragma unroll
    for (int e = 0; e < 8; e++) ones[e] = (short)0x3F80;

    #pragma unroll
    for (int h = 0; h < NH; h++) {
        const float es_r = esl[h * 16 + row16];
        const float* edp = A.ed + ((size_t)b * NH + h) * Nn + jb + grp * 8;
        const short* hb_ = A.ht + ((size_t)b * 96 + h * DIMH) * Nn + jb + grp * 8;
        f32x4_t acc[NT];
        f32x4_t accz = {0.f,0.f,0.f,0.f};
        #pragma unroll
        for (int n = 0; n < NT; n++) acc[n] = (f32x4_t){0.f,0.f,0.f,0.f};
        #pragma unroll
        for (int ks = 0; ks < 8; ks++) {
            u32 bits = adjl[row16][w * 8 + ks] >> (grp * 8);
            float4 e0 = *(const float4*)(edp + ks * 32);
            float4 e1 = *(const float4*)(edp + ks * 32 + 4);
            float ev[8] = {e0.x,e0.y,e0.z,e0.w,e1.x,e1.y,e1.z,e1.w};
            bf16x8_t af;
            #pragma unroll
            for (int e = 0; e < 8; e++) {
                float p = __expf(lrelu_f(es_r + ev[e]));   // |e| small: exp safe without max-shift
                af[e] = f2bf(((bits >> e) & 1) ? p : 0.f);
            }
            #pragma unroll
            for (int n = 0; n < NT; n++) {
                bf16x8_t bf = *(const bf16x8_t*)(hb_ + (size_t)(n * 16 + row16) * Nn + ks * 32);
                acc[n] = __builtin_amdgcn_mfma_f32_16x16x32_bf16(af, bf, acc[n], 0, 0, 0);
            }
            accz = __builtin_amdgcn_mfma_f32_16x16x32_bf16(af, ones, accz, 0, 0, 0);
        }
        #pragma unroll
        for (int n = 0; n < NT; n++) {
            #pragma unroll
            for (int reg = 0; reg < 4; reg++)
                red[w][grp * 4 + reg][n * 16 + row16] = acc[n][reg];
        }
        if (row16 == 0) {
            #pragma unroll
            for (int reg = 0; reg < 4; reg++) redz[w][grp * 4 + reg] = accz[reg];
        }
        __syncthreads();
        #pragma unroll
        for (int idx = t; idx < 16 * DIMH; idx += 256) {
            int r = idx / DIMH, c = idx % DIMH;
            float s = red[0][r][c] + red[1][r][c] + red[2][r][c] + red[3][r][c];
            float z = redz[0][r] + redz[1][r] + redz[2][r] + redz[3][r];
            xrows[r][h * DIMH + c] = elu_f(s / z);
        }
        __syncthreads();
    }

    if (t < 96) {    // column sums -> mean accumulator
        float s = 0.f;
        #pragma unroll
        for (int r = 0; r < 16; r++) s += xrows[r][t];
        atomicAdd(A.ms + b * 96 + t, s);
    }

    for (int job = w; job < A.nmat * 7; job += 4) {   // next-layer GEMMs on local rows
        int mat = job / 7, tile = job - mat * 7;
        const short* Wm = (mat == 0) ? A.W0 : (mat == 1) ? A.W1 : A.W2;
        f32x4_t acc = {0.f,0.f,0.f,0.f};
        #pragma unroll
        for (int ks = 0; ks < 3; ks++) {
            int k0 = ks * 32 + grp * 8;
            bf16x8_t af = cvt8(&xrows[row16][k0]);
            bf16x8_t bf = *(const bf16x8_t*)(Wm + (size_t)(tile * 16 + row16) * 96 + k0);
            acc = __builtin_amdgcn_mfma_f32_16x16x32_bf16(af, bf, acc, 0, 0, 0);
        }
        int col = tile * 16 + row16;
        if (mat == 0 && A.mode0 == 2) {
            if (tile < 6) {
                *(uint2*)(A.oHt + ((size_t)b * 96 + col) * Nn + i0 + grp * 4) =
                    make_uint2(pk2(acc[0], acc[1]), pk2(acc[2], acc[3]));
            } else if (row16 == 0) {
                *(float4*)(A.oEs + (size_t)b * Nn + i0 + grp * 4) = make_float4(acc[0],acc[1],acc[2],acc[3]);
            } else if (row16 == 1) {
                *(float4*)(A.oEd + (size_t)b * Nn + i0 + grp * 4) = make_float4(acc[0],acc[1],acc[2],acc[3]);
            }
        } else {
            float* Td = (mat == 0) ? A.T0 : (mat == 1) ? A.T1 : A.T2;
            *(float4*)(Td + ((size_t)b * 112 + col) * Nn + i0 + grp * 4) =
                make_float4(acc[0], acc[1], acc[2], acc[3]);
        }
    }
}

// =========== gates (redundant per block) + combine U/V -> GAT4/GAT5 inputs ===========
__global__ __launch_bounds__(256) void gates_combine(
    const float* __restrict__ ms1, const float* __restrict__ ms2,
    const float* __restrict__ gw1, const float* __restrict__ gb1,
    const float* __restrict__ gw2, const float* __restrict__ gb2,
    const float* __restrict__ U4, const float* __restrict__ V4,
    const float* __restrict__ U5, const float* __restrict__ V5,
    short* __restrict__ ht4, float* __restrict__ es4, float* __restrict__ ed4,
    short* __restrict__ ht5, float* __restrict__ es5, float* __restrict__ ed5,
    float* __restrict__ gts, float* __restrict__ d_out)
{
    __shared__ float pl[192], hid[48], gsh[2];
    const int t = threadIdx.x, b = blockIdx.z, y = blockIdx.y, rr = blockIdx.x;
    if (t < 192) pl[t] = ((t < 96) ? ms1[b * 96 + t] : ms2[b * 96 + t - 96]) * (1.f / Nn);
    __syncthreads();
    if (t < 48) {
        float a = gb1[t];
        for (int k = 0; k < 192; k++) a += pl[k] * gw1[k * 48 + t];
        hid[t] = elu_f(a);
    }
    __syncthreads();
    if (t < 2) {
        float a = gb2[t];
        for (int k = 0; k < 48; k++) a += hid[k] * gw2[k * 2 + t];
        float g = 1.f / (1.f + __expf(-a));
        gsh[t] = g;
        if (rr == 0 && y == 0) { gts[b * 2 + t] = g; d_out[1024 + t * 8 + b] = g; }
    }
    __syncthreads();
    const float wg = gsh[y];                  // y=0 -> w_t (GAT4), y=1 -> w_r (GAT5)
    size_t off = ((size_t)b * 112 + rr) * Nn + t * 4;
    float4 u = *(const float4*)((y ? U5 : U4) + off);
    float4 v = *(const float4*)((y ? V5 : V4) + off);
    float o0 = (1.f - wg) * u.x + wg * v.x;
    float o1 = (1.f - wg) * u.y + wg * v.y;
    float o2 = (1.f - wg) * u.z + wg * v.z;
    float o3 = (1.f - wg) * u.w + wg * v.w;
    if (rr < 96) {
        short* Hh = (y ? ht5 : ht4) + ((size_t)b * 96 + rr) * Nn + t * 4;
        *(uint2*)Hh = make_uint2(pk2(o0, o1), pk2(o2, o3));
    } else if (rr == 96) {
        *(float4*)((y ? es5 : es4) + (size_t)b * Nn + t * 4) = make_float4(o0, o1, o2, o3);
    } else {
        *(float4*)((y ? ed5 : ed4) + (size_t)b * Nn + t * 4) = make_float4(o0, o1, o2, o3);
    }
}

// =========== combine for GAT3: ht3 = U3 + 0.5*(wt*V34 + wr*V35) ===========
__global__ __launch_bounds__(256) void combine3(
    const float* __restrict__ gts, const float* __restrict__ U3,
    const float* __restrict__ V34, const float* __restrict__ V35,
    short* __restrict__ ht3, float* __restrict__ es3, float* __restrict__ ed3)
{
    const int t = threadIdx.x, b = blockIdx.z, rr = blockIdx.x;
    const float wt = gts[b * 2], wr = gts[b * 2 + 1];
    size_t off = ((size_t)b * 112 + rr) * Nn + t * 4;
    float4 u = *(const float4*)(U3 + off);
    float4 p = *(const float4*)(V34 + off);
    float4 q = *(const float4*)(V35 + off);
    float o0 = u.x + 0.5f * (wt * p.x + wr * q.x);
    float o1 = u.y + 0.5f * (wt * p.y + wr * q.y);
    float o2 = u.z + 0.5f * (wt * p.z + wr * q.z);
    float o3 = u.w + 0.5f * (wt * p.w + wr * q.w);
    if (rr < 96) {
        *(uint2*)(ht3 + ((size_t)b * 96 + rr) * Nn + t * 4) = make_uint2(pk2(o0, o1), pk2(o2, o3));
    } else if (rr == 96) {
        *(float4*)(es3 + (size_t)b * Nn + t * 4) = make_float4(o0, o1, o2, o3);
    } else {
        *(float4*)(ed3 + (size_t)b * Nn + t * 4) = make_float4(o0, o1, o2, o3);
    }
}

// =========== final projection ===========
__global__ __launch_bounds__(128) void proj_kernel(
    const float* __restrict__ x3s, const float* __restrict__ x4s, const float* __restrict__ x5s,
    const float* __restrict__ w, const float* __restrict__ bias, float* __restrict__ d_out)
{
    __shared__ float tok[288];
    const int b = blockIdx.x, t = threadIdx.x;
    if (t < 96) {
        tok[t]       = x3s[b * 96 + t] * (1.f / Nn);
        tok[96 + t]  = x4s[b * 96 + t] * (1.f / Nn);
        tok[192 + t] = x5s[b * 96 + t] * (1.f / Nn);
    }
    __syncthreads();
    float acc = bias[t];
    for (int k = 0; k < 288; k++) acc += tok[k] * w[k * 128 + t];
    d_out[b * 128 + t] = elu_f(acc);
}

extern "C" void kernel_launch(void* const* d_in, const int* in_sizes, int n_in,
                              void* d_out, int out_size, void* d_ws, size_t ws_size,
                              hipStream_t stream)
{
    const float* x     = (const float*)d_in[0];
    const int*   adj   = (const int*)d_in[1];
    const float* ln_g  = (const float*)d_in[2];
    const float* ln_b  = (const float*)d_in[3];
    const float* pre_w = (const float*)d_in[4];
    const float* pre_b = (const float*)d_in[5];
    const float* g_w[5]  = {(const float*)d_in[6],  (const float*)d_in[9],  (const float*)d_in[12],
                            (const float*)d_in[15], (const float*)d_in[18]};
    const float* g_as[5] = {(const float*)d_in[7],  (const float*)d_in[10], (const float*)d_in[13],
                            (const float*)d_in[16], (const float*)d_in[19]};
    const float* g_ad[5] = {(const float*)d_in[8],  (const float*)d_in[11], (const float*)d_in[14],
                            (const float*)d_in[17], (const float*)d_in[20]};
    const float* gw1 = (const float*)d_in[21];
    const float* gb1 = (const float*)d_in[22];
    const float* gw2 = (const float*)d_in[23];
    const float* gb2 = (const float*)d_in[24];
    const float* pw  = (const float*)d_in[25];
    const float* pb  = (const float*)d_in[26];
    float* out = (float*)d_out;

    // -------- workspace layout --------
    float* F = (float*)d_ws;
    const size_t SZT = (size_t)Bq * 112 * Nn;
    float* msb = F;
    float* ms1 = msb, *ms2 = msb + 768, *ms3 = msb + 1536, *ms4 = msb + 2304, *ms5 = msb + 3072;
    float* gts = msb + 3840;
    float* es1 = msb + 3856;
    float* ed1 = es1 + 24576;
    float* es2 = ed1 + 24576; float* ed2 = es2 + 8192;
    float* es3 = ed2 + 8192;  float* ed3 = es3 + 8192;
    float* es4 = ed3 + 8192;  float* ed4 = es4 + 8192;
    float* es5 = ed4 + 8192;  float* ed5 = es5 + 8192;
    float* U4  = ed5 + 8192;
    float* U5  = U4 + SZT;
    float* V4  = U5 + SZT;
    float* V5  = V4 + SZT;
    float* U3  = V5 + SZT;
    float* V34 = U3 + SZT;
    float* V35 = V34 + SZT;
    u32*  adjp = (u32*)(V35 + SZT);
    short* wtb = (short*)(adjp + 32768);
    short* wpre = wtb + 5 * 10752;
    short* ht1 = wpre + 6144;
    short* ht2 = ht1 + (size_t)Bq * 96 * Nn;
    short* ht3 = ht2 + (size_t)Bq * 96 * Nn;
    short* ht4 = ht3 + (size_t)Bq * 96 * Nn;
    short* ht5 = ht4 + (size_t)Bq * 96 * Nn;

    const dim3 blk(256);

    {
        PrepP P;
        P.W0 = g_w[0]; P.W1 = g_w[1]; P.W2 = g_w[2]; P.W3 = g_w[3]; P.W4 = g_w[4];
        P.s0 = g_as[0]; P.s1 = g_as[1]; P.s2 = g_as[2]; P.s3 = g_as[3]; P.s4 = g_as[4];
        P.d0 = g_ad[0]; P.d1 = g_ad[1]; P.d2 = g_ad[2]; P.d3 = g_ad[3]; P.d4 = g_ad[4];
        setup_kernel<<<dim3(378), blk, 0, stream>>>(P, adj, pre_w, adjp, wtb, wpre, msb);
    }

    pre_h1<<<dim3(512), blk, 0, stream>>>(x, ln_g, ln_b, wpre, pre_b, wtb, ht1, es1, ed1);

    {   // GAT1 attention -> x1 rows; fused h2 (final) + U4 + U5
        WSArgs B; B.es = es1; B.ed = ed1; B.ht = ht1; B.ms = ms1;
        B.nmat = 3; B.mode0 = 2;
        B.W0 = wtb + 1 * 10752; B.W1 = wtb + 3 * 10752; B.W2 = wtb + 4 * 10752;
        B.T0 = nullptr; B.T1 = U4; B.T2 = U5;
        B.oHt = ht2; B.oEs = es2; B.oEd = ed2;
        ws_fused<3><<<dim3(64, 1, Bq), blk, 0, stream>>>(adjp, B, B);
    }
    {   // GAT2 attention -> x2 rows; fused V4 + V5 + U3
        WSArgs C; C.es = es2; C.ed = ed2; C.ht = ht2; C.ms = ms2;
        C.nmat = 3; C.mode0 = 1;
        C.W0 = wtb + 3 * 10752; C.W1 = wtb + 4 * 10752; C.W2 = wtb + 2 * 10752;
        C.T0 = V4; C.T1 = V5; C.T2 = U3;
        C.oHt = nullptr; C.oEs = nullptr; C.oEd = nullptr;
        ws_fused<1><<<dim3(64, 1, Bq), blk, 0, stream>>>(adjp, C, C);
    }
    gates_combine<<<dim3(98, 2, Bq), blk, 0, stream>>>(ms1, ms2, gw1, gb1, gw2, gb2,
                                                       U4, V4, U5, V5,
                                                       ht4, es4, ed4, ht5, es5, ed5, gts, out);
    {   // GAT4 + GAT5 attention (dual); fused V34 / V35
        WSArgs E0; E0.es = es4; E0.ed = ed4; E0.ht = ht4; E0.ms = ms4;
        E0.nmat = 1; E0.mode0 = 1; E0.W0 = wtb + 2 * 10752; E0.W1 = nullptr; E0.W2 = nullptr;
        E0.T0 = V34; E0.T1 = nullptr; E0.T2 = nullptr;
        E0.oHt = nullptr; E0.oEs = nullptr; E0.oEd = nullptr;
        WSArgs E1 = E0;
        E1.es = es5; E1.ed = ed5; E1.ht = ht5; E1.ms = ms5; E1.T0 = V35;
        ws_fused<1><<<dim3(64, 2, Bq), blk, 0, stream>>>(adjp, E0, E1);
    }
    combine3<<<dim3(98, 1, Bq), blk, 0, stream>>>(gts, U3, V34, V35, ht3, es3, ed3);
    {   // GAT3 attention -> ms3 only
        WSArgs G; G.es = es3; G.ed = ed3; G.ht = ht3; G.ms = ms3;
        G.nmat = 0; G.mode0 = 1;
        G.W0 = nullptr; G.W1 = nullptr; G.W2 = nullptr;
        G.T0 = nullptr; G.T1 = nullptr; G.T2 = nullptr;
        G.oHt = nullptr; G.oEs = nullptr; G.oEd = nullptr;
        ws_fused<1><<<dim3(64, 1, Bq), blk, 0, stream>>>(adjp, G, G);
    }
    proj_kernel<<<dim3(Bq), dim3(128), 0, stream>>>(ms3, ms4, ms5, pw, pb, out);
}

// Round 6
// 237.231 us; speedup vs baseline: 2.9048x; 1.0226x over previous
//
#include <hip/hip_runtime.h>
#include <math.h>

#define Bq 8
#define Nn 1024

typedef __attribute__((ext_vector_type(8))) short bf16x8_t;
typedef __attribute__((ext_vector_type(4))) float f32x4_t;
typedef unsigned int u32;

__device__ __forceinline__ float elu_f(float x){ return x > 0.f ? x : __expf(x) - 1.f; }
__device__ __forceinline__ float lrelu_f(float x){ return x > 0.f ? x : 0.2f * x; }
__device__ __forceinline__ short f2bf(float f){            // RNE float->bf16
    union { float f; u32 u; } v; v.f = f;
    return (short)((v.u + 0x7FFFu + ((v.u >> 16) & 1u)) >> 16);
}
__device__ __forceinline__ u32 pk2(float a, float b){
    return (u32)(unsigned short)f2bf(a) | ((u32)(unsigned short)f2bf(b) << 16);
}
__device__ __forceinline__ bf16x8_t cvt8(const float* p){
    bf16x8_t r;
    #pragma unroll
    for (int e = 0; e < 8; e++) r[e] = f2bf(p[e]);
    return r;
}

// =========== setup: pack adj bits, build extended bf16 weights, zero accumulators ===========
// Wte[g][c][k]: c<96 -> W[k][c];  c=96+q (q<H) -> (W @ a_src_head_q)[k];  c=96+H+q -> (W @ a_dst_head_q)[k]
struct PrepP {
    const float *W0,*W1,*W2,*W3,*W4;
    const float *s0,*s1,*s2,*s3,*s4;
    const float *d0,*d1,*d2,*d3,*d4;
};

__global__ __launch_bounds__(256) void setup_kernel(
    PrepP P, const int* __restrict__ adj, const float* __restrict__ pre_w,
    u32* __restrict__ adjp, short* __restrict__ wtb, short* __restrict__ wpre,
    float* __restrict__ msz)
{
    const int bid = blockIdx.x, t = threadIdx.x;
    if (bid < 128) {                      // pack adj -> bitmask [1024][32]
        int w = bid * 256 + t;
        int row = w >> 5, wc = w & 31;
        const int* p = adj + (size_t)row * Nn + wc * 32;
        u32 bset = 0;
        #pragma unroll
        for (int e = 0; e < 32; e++) bset |= (p[e] > 0 ? 1u : 0u) << e;
        adjp[w] = bset;
    } else if (bid < 338) {               // extended W: 5 x 112 x 96
        int idx = (bid - 128) * 256 + t;
        int g = idx / 10752, rem = idx % 10752;
        int c = rem / 96, k = rem % 96;
        const float* W  = (g==0)?P.W0:(g==1)?P.W1:(g==2)?P.W2:(g==3)?P.W3:P.W4;
        const float* as = (g==0)?P.s0:(g==1)?P.s1:(g==2)?P.s2:(g==3)?P.s3:P.s4;
        const float* ad = (g==0)?P.d0:(g==1)?P.d1:(g==2)?P.d2:(g==3)?P.d3:P.d4;
        const int H = (g == 0) ? 3 : 1, dim = 96 / H;
        float v = 0.f;
        if (c < 96) v = W[k * 96 + c];
        else {
            int q = c - 96;
            if (q < H) {
                int base = q * dim; float s = 0.f;
                for (int d = 0; d < dim; d++) s += W[k * 96 + base + d] * as[base + d];
                v = s;
            } else if (q < 2 * H) {
                int base = (q - H) * dim; float s = 0.f;
                for (int d = 0; d < dim; d++) s += W[k * 96 + base + d] * ad[base + d];
                v = s;
            }
        }
        wtb[idx] = f2bf(v);
    } else if (bid < 362) {               // pre_w transposed [96][64] bf16
        int idx = (bid - 338) * 256 + t;
        int c = idx >> 6, k = idx & 63;
        wpre[idx] = f2bf(pre_w[k * 96 + c]);
    } else {                              // zero ms1..ms5 + gts
        int idx = (bid - 362) * 256 + t;
        if (idx < 3856) msz[idx] = 0.f;
    }
}

// =========== pre (LN + Linear 64->96 + ELU) fused with h1 GEMM + es1/ed1 ===========
__global__ __launch_bounds__(256) void pre_h1(
    const float* __restrict__ x, const float* __restrict__ ln_g, const float* __restrict__ ln_b,
    const short* __restrict__ wpre, const float* __restrict__ pre_b,
    const short* __restrict__ Wt1, short* __restrict__ ht1,
    float* __restrict__ es1, float* __restrict__ ed1)
{
    __shared__ short xsA[16][72];     // bf16 LN'd input rows
    __shared__ float xs0[16][100];    // fp32 x0 rows
    const int t = threadIdx.x;
    const int bid = blockIdx.x;
    const int b = bid >> 6, n0 = (bid & 63) * 16;
    {
        int r = t >> 4, c4 = t & 15;
        float4 v = *(const float4*)(x + ((size_t)b * Nn + n0 + r) * 64 + c4 * 4);
        float s = v.x + v.y + v.z + v.w;
        float s2 = v.x*v.x + v.y*v.y + v.z*v.z + v.w*v.w;
        #pragma unroll
        for (int m = 1; m < 16; m <<= 1) { s += __shfl_xor(s, m); s2 += __shfl_xor(s2, m); }
        float mu = s * (1.f / 64), rv = rsqrtf(s2 * (1.f / 64) - mu * mu + 1e-5f);
        float4 g = *(const float4*)(ln_g + c4 * 4);
        float4 bb = *(const float4*)(ln_b + c4 * 4);
        float xn0 = (v.x - mu) * rv * g.x + bb.x;
        float xn1 = (v.y - mu) * rv * g.y + bb.y;
        float xn2 = (v.z - mu) * rv * g.z + bb.z;
        float xn3 = (v.w - mu) * rv * g.w + bb.w;
        *(uint2*)&xsA[r][c4 * 4] = make_uint2(pk2(xn0, xn1), pk2(xn2, xn3));
    }
    __syncthreads();
    const int lane = t & 63, w = t >> 6;
    const int row16 = lane & 15, grp = lane >> 4;
    for (int tile = w; tile < 6; tile += 4) {    // pre GEMM (K=64)
        f32x4_t acc = {0.f,0.f,0.f,0.f};
        #pragma unroll
        for (int ks = 0; ks < 2; ks++) {
            int k0 = ks * 32 + grp * 8;
            bf16x8_t af = *(const bf16x8_t*)&xsA[row16][k0];
            bf16x8_t bf = *(const bf16x8_t*)(wpre + (size_t)(tile * 16 + row16) * 64 + k0);
            acc = __builtin_amdgcn_mfma_f32_16x16x32_bf16(af, bf, acc, 0, 0, 0);
        }
        int col = tile * 16 + row16;
        float pbv = pre_b[col];
        #pragma unroll
        for (int reg = 0; reg < 4; reg++)
            xs0[grp * 4 + reg][col] = elu_f(acc[reg] + pbv);
    }
    __syncthreads();
    for (int tile = w; tile < 7; tile += 4) {    // h1 GEMM (K=96) + es/ed tile
        f32x4_t acc = {0.f,0.f,0.f,0.f};
        #pragma unroll
        for (int ks = 0; ks < 3; ks++) {
            int k0 = ks * 32 + grp * 8;
            bf16x8_t af = cvt8(&xs0[row16][k0]);
            bf16x8_t bf = *(const bf16x8_t*)(Wt1 + (size_t)(tile * 16 + row16) * 96 + k0);
            acc = __builtin_amdgcn_mfma_f32_16x16x32_bf16(af, bf, acc, 0, 0, 0);
        }
        int col = tile * 16 + row16;
        if (tile < 6) {
            *(uint2*)(ht1 + ((size_t)b * 96 + col) * Nn + n0 + grp * 4) =
                make_uint2(pk2(acc[0], acc[1]), pk2(acc[2], acc[3]));
        } else {
            int q = row16;
            if (q < 3)
                *(float4*)(es1 + ((size_t)b * 3 + q) * Nn + n0 + grp * 4) =
                    make_float4(acc[0], acc[1], acc[2], acc[3]);
            else if (q < 6)
                *(float4*)(ed1 + ((size_t)b * 3 + (q - 3)) * Nn + n0 + grp * 4) =
                    make_float4(acc[0], acc[1], acc[2], acc[3]);
        }
    }
}

// =========== fused GAT step: attention (P@h via MFMA, 8-wave split-K) + next-layer GEMMs ===========
struct WSArgs {
    const float *es, *ed;        // [b][NH][1024]
    const short *ht;             // [b][96][1024] bf16
    float *ms;                   // [b][96] column-sum accumulator
    int nmat, mode0;             // mode0: 1 = fp32 T-buf, 2 = final bf16 ht + es/ed
    const short *W0, *W1, *W2;   // extended weights [112][96]
    float *T0, *T1, *T2;         // fp32 T-bufs [b][112][1024]
    short *oHt; float *oEs, *oEd;
};

template<int NH>
__global__ __launch_bounds__(512) void ws_fused(const u32* __restrict__ adjp, WSArgs a0, WSArgs a1)
{
    constexpr int DIMH = 96 / NH, NT = DIMH / 16;
    __shared__ float xrows[16][100];
    __shared__ float red[8][16][97];
    __shared__ float redz[8][16];
    __shared__ u32 adjl[16][33];
    __shared__ float esl[NH * 16];
    __shared__ float edl[NH * 1024];
    const int t = threadIdx.x;
    const int i0 = blockIdx.x * 16, b = blockIdx.z;
    const WSArgs A = blockIdx.y ? a1 : a0;

    if (t < 128) {
        int r = t >> 3, w4 = (t & 7) * 4;
        uint4 wv = *(const uint4*)(adjp + (size_t)(i0 + r) * 32 + w4);
        adjl[r][w4] = wv.x; adjl[r][w4+1] = wv.y; adjl[r][w4+2] = wv.z; adjl[r][w4+3] = wv.w;
    }
    if (t < NH * 16)
        esl[t] = A.es[((size_t)b * NH + (t >> 4)) * Nn + i0 + (t & 15)];
    for (int idx = t; idx < NH * 256; idx += 512)      // stage ed rows (coalesced)
        ((float4*)edl)[idx] = ((const float4*)(A.ed + (size_t)b * NH * Nn))[idx];
    __syncthreads();

    const int lane = t & 63, w = t >> 6;               // 8 waves, each 128 j
    const int row16 = lane & 15, grp = lane >> 4;
    const int jb = w * 128;
    bf16x8_t ones;
    #pragma unroll
    for (int e = 0; e < 8; e++) ones[e] = (short)0x3F80;

    #pragma unroll
    for (int h = 0; h < NH; h++) {
        const float es_r = esl[h * 16 + row16];
        const float* edp = edl + h * Nn + jb + grp * 8;
        const short* hb_ = A.ht + ((size_t)b * 96 + h * DIMH) * Nn + jb + grp * 8;
        f32x4_t acc[NT];
        f32x4_t accz = {0.f,0.f,0.f,0.f};
        #pragma unroll
        for (int n = 0; n < NT; n++) acc[n] = (f32x4_t){0.f,0.f,0.f,0.f};
        #pragma unroll
        for (int ks = 0; ks < 4; ks++) {
            u32 bits = adjl[row16][w * 4 + ks] >> (grp * 8);
            float4 e0 = *(const float4*)(edp + ks * 32);
            float4 e1 = *(const float4*)(edp + ks * 32 + 4);
            float ev[8] = {e0.x,e0.y,e0.z,e0.w,e1.x,e1.y,e1.z,e1.w};
            bf16x8_t af;
            #pragma unroll
            for (int e = 0; e < 8; e++) {
                float p = __expf(lrelu_f(es_r + ev[e]));   // |e| small: exp safe without max-shift
                af[e] = f2bf(((bits >> e) & 1) ? p : 0.f);
            }
            #pragma unroll
            for (int n = 0; n < NT; n++) {
                bf16x8_t bf = *(const bf16x8_t*)(hb_ + (size_t)(n * 16 + row16) * Nn + ks * 32);
                acc[n] = __builtin_amdgcn_mfma_f32_16x16x32_bf16(af, bf, acc[n], 0, 0, 0);
            }
            accz = __builtin_amdgcn_mfma_f32_16x16x32_bf16(af, ones, accz, 0, 0, 0);
        }
        #pragma unroll
        for (int n = 0; n < NT; n++) {
            #pragma unroll
            for (int reg = 0; reg < 4; reg++)
                red[w][grp * 4 + reg][n * 16 + row16] = acc[n][reg];
        }
        if (row16 == 0) {
            #pragma unroll
            for (int reg = 0; reg < 4; reg++) redz[w][grp * 4 + reg] = accz[reg];
        }
        __syncthreads();
        for (int idx = t; idx < 16 * DIMH; idx += 512) {
            int r = idx / DIMH, c = idx % DIMH;
            float s = 0.f, z = 0.f;
            #pragma unroll
            for (int ww = 0; ww < 8; ww++) { s += red[ww][r][c]; z += redz[ww][r]; }
            xrows[r][h * DIMH + c] = elu_f(s / z);
        }
        __syncthreads();
    }

    if (t < 96) {    // column sums -> mean accumulator
        float s = 0.f;
        #pragma unroll
        for (int r = 0; r < 16; r++) s += xrows[r][t];
        atomicAdd(A.ms + b * 96 + t, s);
    }

    for (int job = w; job < A.nmat * 7; job += 8) {   // next-layer GEMMs on local rows
        int mat = job / 7, tile = job - mat * 7;
        const short* Wm = (mat == 0) ? A.W0 : (mat == 1) ? A.W1 : A.W2;
        f32x4_t acc = {0.f,0.f,0.f,0.f};
        #pragma unroll
        for (int ks = 0; ks < 3; ks++) {
            int k0 = ks * 32 + grp * 8;
            bf16x8_t af = cvt8(&xrows[row16][k0]);
            bf16x8_t bf = *(const bf16x8_t*)(Wm + (size_t)(tile * 16 + row16) * 96 + k0);
            acc = __builtin_amdgcn_mfma_f32_16x16x32_bf16(af, bf, acc, 0, 0, 0);
        }
        int col = tile * 16 + row16;
        if (mat == 0 && A.mode0 == 2) {
            if (tile < 6) {
                *(uint2*)(A.oHt + ((size_t)b * 96 + col) * Nn + i0 + grp * 4) =
                    make_uint2(pk2(acc[0], acc[1]), pk2(acc[2], acc[3]));
            } else if (row16 == 0) {
                *(float4*)(A.oEs + (size_t)b * Nn + i0 + grp * 4) = make_float4(acc[0],acc[1],acc[2],acc[3]);
            } else if (row16 == 1) {
                *(float4*)(A.oEd + (size_t)b * Nn + i0 + grp * 4) = make_float4(acc[0],acc[1],acc[2],acc[3]);
            }
        } else {
            float* Td = (mat == 0) ? A.T0 : (mat == 1) ? A.T1 : A.T2;
            *(float4*)(Td + ((size_t)b * 112 + col) * Nn + i0 + grp * 4) =
                make_float4(acc[0], acc[1], acc[2], acc[3]);
        }
    }
}

// =========== gates (redundant per block) + combine U/V -> GAT4/GAT5 inputs ===========
__global__ __launch_bounds__(256) void gates_combine(
    const float* __restrict__ ms1, const float* __restrict__ ms2,
    const float* __restrict__ gw1, const float* __restrict__ gb1,
    const float* __restrict__ gw2, const float* __restrict__ gb2,
    const float* __restrict__ U4, const float* __restrict__ V4,
    const float* __restrict__ U5, const float* __restrict__ V5,
    short* __restrict__ ht4, float* __restrict__ es4, float* __restrict__ ed4,
    short* __restrict__ ht5, float* __restrict__ es5, float* __restrict__ ed5,
    float* __restrict__ gts, float* __restrict__ d_out)
{
    __shared__ float pl[192], hid[48], gsh[2];
    const int t = threadIdx.x, b = blockIdx.z, y = blockIdx.y, rr = blockIdx.x;
    if (t < 192) pl[t] = ((t < 96) ? ms1[b * 96 + t] : ms2[b * 96 + t - 96]) * (1.f / Nn);
    __syncthreads();
    if (t < 48) {
        float a = gb1[t];
        for (int k = 0; k < 192; k++) a += pl[k] * gw1[k * 48 + t];
        hid[t] = elu_f(a);
    }
    __syncthreads();
    if (t < 2) {
        float a = gb2[t];
        for (int k = 0; k < 48; k++) a += hid[k] * gw2[k * 2 + t];
        float g = 1.f / (1.f + __expf(-a));
        gsh[t] = g;
        if (rr == 0 && y == 0) { gts[b * 2 + t] = g; d_out[1024 + t * 8 + b] = g; }
    }
    __syncthreads();
    const float wg = gsh[y];                  // y=0 -> w_t (GAT4), y=1 -> w_r (GAT5)
    size_t off = ((size_t)b * 112 + rr) * Nn + t * 4;
    float4 u = *(const float4*)((y ? U5 : U4) + off);
    float4 v = *(const float4*)((y ? V5 : V4) + off);
    float o0 = (1.f - wg) * u.x + wg * v.x;
    float o1 = (1.f - wg) * u.y + wg * v.y;
    float o2 = (1.f - wg) * u.z + wg * v.z;
    float o3 = (1.f - wg) * u.w + wg * v.w;
    if (rr < 96) {
        short* Hh = (y ? ht5 : ht4) + ((size_t)b * 96 + rr) * Nn + t * 4;
        *(uint2*)Hh = make_uint2(pk2(o0, o1), pk2(o2, o3));
    } else if (rr == 96) {
        *(float4*)((y ? es5 : es4) + (size_t)b * Nn + t * 4) = make_float4(o0, o1, o2, o3);
    } else {
        *(float4*)((y ? ed5 : ed4) + (size_t)b * Nn + t * 4) = make_float4(o0, o1, o2, o3);
    }
}

// =========== combine for GAT3: ht3 = U3 + 0.5*(wt*V34 + wr*V35) ===========
__global__ __launch_bounds__(256) void combine3(
    const float* __restrict__ gts, const float* __restrict__ U3,
    const float* __restrict__ V34, const float* __restrict__ V35,
    short* __restrict__ ht3, float* __restrict__ es3, float* __restrict__ ed3)
{
    const int t = threadIdx.x, b = blockIdx.z, rr = blockIdx.x;
    const float wt = gts[b * 2], wr = gts[b * 2 + 1];
    size_t off = ((size_t)b * 112 + rr) * Nn + t * 4;
    float4 u = *(const float4*)(U3 + off);
    float4 p = *(const float4*)(V34 + off);
    float4 q = *(const float4*)(V35 + off);
    float o0 = u.x + 0.5f * (wt * p.x + wr * q.x);
    float o1 = u.y + 0.5f * (wt * p.y + wr * q.y);
    float o2 = u.z + 0.5f * (wt * p.z + wr * q.z);
    float o3 = u.w + 0.5f * (wt * p.w + wr * q.w);
    if (rr < 96) {
        *(uint2*)(ht3 + ((size_t)b * 96 + rr) * Nn + t * 4) = make_uint2(pk2(o0, o1), pk2(o2, o3));
    } else if (rr == 96) {
        *(float4*)(es3 + (size_t)b * Nn + t * 4) = make_float4(o0, o1, o2, o3);
    } else {
        *(float4*)(ed3 + (size_t)b * Nn + t * 4) = make_float4(o0, o1, o2, o3);
    }
}

// =========== final projection ===========
__global__ __launch_bounds__(128) void proj_kernel(
    const float* __restrict__ x3s, const float* __restrict__ x4s, const float* __restrict__ x5s,
    const float* __restrict__ w, const float* __restrict__ bias, float* __restrict__ d_out)
{
    __shared__ float tok[288];
    const int b = blockIdx.x, t = threadIdx.x;
    if (t < 96) {
        tok[t]       = x3s[b * 96 + t] * (1.f / Nn);
        tok[96 + t]  = x4s[b * 96 + t] * (1.f / Nn);
        tok[192 + t] = x5s[b * 96 + t] * (1.f / Nn);
    }
    __syncthreads();
    float acc = bias[t];
    for (int k = 0; k < 288; k++) acc += tok[k] * w[k * 128 + t];
    d_out[b * 128 + t] = elu_f(acc);
}

extern "C" void kernel_launch(void* const* d_in, const int* in_sizes, int n_in,
                              void* d_out, int out_size, void* d_ws, size_t ws_size,
                              hipStream_t stream)
{
    const float* x     = (const float*)d_in[0];
    const int*   adj   = (const int*)d_in[1];
    const float* ln_g  = (const float*)d_in[2];
    const float* ln_b  = (const float*)d_in[3];
    const float* pre_w = (const float*)d_in[4];
    const float* pre_b = (const float*)d_in[5];
    const float* g_w[5]  = {(const float*)d_in[6],  (const float*)d_in[9],  (const float*)d_in[12],
                            (const float*)d_in[15], (const float*)d_in[18]};
    const float* g_as[5] = {(const float*)d_in[7],  (const float*)d_in[10], (const float*)d_in[13],
                            (const float*)d_in[16], (const float*)d_in[19]};
    const float* g_ad[5] = {(const float*)d_in[8],  (const float*)d_in[11], (const float*)d_in[14],
                            (const float*)d_in[17], (const float*)d_in[20]};
    const float* gw1 = (const float*)d_in[21];
    const float* gb1 = (const float*)d_in[22];
    const float* gw2 = (const float*)d_in[23];
    const float* gb2 = (const float*)d_in[24];
    const float* pw  = (const float*)d_in[25];
    const float* pb  = (const float*)d_in[26];
    float* out = (float*)d_out;

    // -------- workspace layout --------
    float* F = (float*)d_ws;
    const size_t SZT = (size_t)Bq * 112 * Nn;
    float* msb = F;
    float* ms1 = msb, *ms2 = msb + 768, *ms3 = msb + 1536, *ms4 = msb + 2304, *ms5 = msb + 3072;
    float* gts = msb + 3840;
    float* es1 = msb + 3856;
    float* ed1 = es1 + 24576;
    float* es2 = ed1 + 24576; float* ed2 = es2 + 8192;
    float* es3 = ed2 + 8192;  float* ed3 = es3 + 8192;
    float* es4 = ed3 + 8192;  float* ed4 = es4 + 8192;
    float* es5 = ed4 + 8192;  float* ed5 = es5 + 8192;
    float* U4  = ed5 + 8192;
    float* U5  = U4 + SZT;
    float* V4  = U5 + SZT;
    float* V5  = V4 + SZT;
    float* U3  = V5 + SZT;
    float* V34 = U3 + SZT;
    float* V35 = V34 + SZT;
    u32*  adjp = (u32*)(V35 + SZT);
    short* wtb = (short*)(adjp + 32768);
    short* wpre = wtb + 5 * 10752;
    short* ht1 = wpre + 6144;
    short* ht2 = ht1 + (size_t)Bq * 96 * Nn;
    short* ht3 = ht2 + (size_t)Bq * 96 * Nn;
    short* ht4 = ht3 + (size_t)Bq * 96 * Nn;
    short* ht5 = ht4 + (size_t)Bq * 96 * Nn;

    const dim3 blk(256), blk512(512);

    {
        PrepP P;
        P.W0 = g_w[0]; P.W1 = g_w[1]; P.W2 = g_w[2]; P.W3 = g_w[3]; P.W4 = g_w[4];
        P.s0 = g_as[0]; P.s1 = g_as[1]; P.s2 = g_as[2]; P.s3 = g_as[3]; P.s4 = g_as[4];
        P.d0 = g_ad[0]; P.d1 = g_ad[1]; P.d2 = g_ad[2]; P.d3 = g_ad[3]; P.d4 = g_ad[4];
        setup_kernel<<<dim3(378), blk, 0, stream>>>(P, adj, pre_w, adjp, wtb, wpre, msb);
    }

    pre_h1<<<dim3(512), blk, 0, stream>>>(x, ln_g, ln_b, wpre, pre_b, wtb, ht1, es1, ed1);

    {   // GAT1 attention -> x1 rows; fused h2 (final) + U4 + U5
        WSArgs B; B.es = es1; B.ed = ed1; B.ht = ht1; B.ms = ms1;
        B.nmat = 3; B.mode0 = 2;
        B.W0 = wtb + 1 * 10752; B.W1 = wtb + 3 * 10752; B.W2 = wtb + 4 * 10752;
        B.T0 = nullptr; B.T1 = U4; B.T2 = U5;
        B.oHt = ht2; B.oEs = es2; B.oEd = ed2;
        ws_fused<3><<<dim3(64, 1, Bq), blk512, 0, stream>>>(adjp, B, B);
    }
    {   // GAT2 attention -> x2 rows; fused V4 + V5 + U3
        WSArgs C; C.es = es2; C.ed = ed2; C.ht = ht2; C.ms = ms2;
        C.nmat = 3; C.mode0 = 1;
        C.W0 = wtb + 3 * 10752; C.W1 = wtb + 4 * 10752; C.W2 = wtb + 2 * 10752;
        C.T0 = V4; C.T1 = V5; C.T2 = U3;
        C.oHt = nullptr; C.oEs = nullptr; C.oEd = nullptr;
        ws_fused<1><<<dim3(64, 1, Bq), blk512, 0, stream>>>(adjp, C, C);
    }
    gates_combine<<<dim3(98, 2, Bq), blk, 0, stream>>>(ms1, ms2, gw1, gb1, gw2, gb2,
                                                       U4, V4, U5, V5,
                                                       ht4, es4, ed4, ht5, es5, ed5, gts, out);
    {   // GAT4 + GAT5 attention (dual); fused V34 / V35
        WSArgs E0; E0.es = es4; E0.ed = ed4; E0.ht = ht4; E0.ms = ms4;
        E0.nmat = 1; E0.mode0 = 1; E0.W0 = wtb + 2 * 10752; E0.W1 = nullptr; E0.W2 = nullptr;
        E0.T0 = V34; E0.T1 = nullptr; E0.T2 = nullptr;
        E0.oHt = nullptr; E0.oEs = nullptr; E0.oEd = nullptr;
        WSArgs E1 = E0;
        E1.es = es5; E1.ed = ed5; E1.ht = ht5; E1.ms = ms5; E1.T0 = V35;
        ws_fused<1><<<dim3(64, 2, Bq), blk512, 0, stream>>>(adjp, E0, E1);
    }
    combine3<<<dim3(98, 1, Bq), blk, 0, stream>>>(gts, U3, V34, V35, ht3, es3, ed3);
    {   // GAT3 attention -> ms3 only
        WSArgs G; G.es = es3; G.ed = ed3; G.ht = ht3; G.ms = ms3;
        G.nmat = 0; G.mode0 = 1;
        G.W0 = nullptr; G.W1 = nullptr; G.W2 = nullptr;
        G.T0 = nullptr; G.T1 = nullptr; G.T2 = nullptr;
        G.oHt = nullptr; G.oEs = nullptr; G.oEd = nullptr;
        ws_fused<1><<<dim3(64, 1, Bq), blk512, 0, stream>>>(adjp, G, G);
    }
    proj_kernel<<<dim3(Bq), dim3(128), 0, stream>>>(ms3, ms4, ms5, pw, pb, out);
}